// Round 2
// baseline (426.718 us; speedup 1.0000x reference)
//
#include <hip/hip_runtime.h>
#include <hip/hip_bf16.h>
#include <cstdint>

// ---------- types / helpers ----------
typedef __attribute__((ext_vector_type(8))) short bf16x8;   // 8 bf16 in 4 VGPRs
typedef __attribute__((ext_vector_type(4))) float f32x4;

#define MFMA16(a, b, c) __builtin_amdgcn_mfma_f32_16x16x32_bf16((a), (b), (c), 0, 0, 0)

static __device__ __forceinline__ unsigned short f2b(float x) {
  __hip_bfloat16 h = __float2bfloat16(x);
  return __builtin_bit_cast(unsigned short, h);
}

static __device__ __forceinline__ void gload16(const void* g, void* l) {
  __builtin_amdgcn_global_load_lds((const __attribute__((address_space(1))) void*)g,
                                   (__attribute__((address_space(3))) void*)l, 16, 0, 0);
}

// ---------- f32 -> bf16 elementwise convert ----------
__global__ __launch_bounds__(256) void cvt_f32_bf16(const float* __restrict__ s,
                                                    __hip_bfloat16* __restrict__ d, int n) {
  int stride = gridDim.x * 256 * 4;
  for (int i = (blockIdx.x * 256 + threadIdx.x) * 4; i < n; i += stride) {
    float4 v = *(const float4*)(s + i);
    ushort4 o;
    o.x = f2b(v.x); o.y = f2b(v.y); o.z = f2b(v.z); o.w = f2b(v.w);
    *(ushort4*)&d[i] = o;
  }
}

// ---------- transpose-convert weights: dst[p][n][k] = (bf16) src_p[k][n], zero pad n in [N,Npad) ----------
__global__ __launch_bounds__(256) void transpose_cvt(const float* __restrict__ s0,
                                                     const float* __restrict__ s1,
                                                     const float* __restrict__ s2,
                                                     __hip_bfloat16* __restrict__ dst,
                                                     int K, int N, int Npad) {
  __shared__ float tile[32][33];
  int p = blockIdx.z;
  const float* src = (p == 0) ? s0 : (p == 1) ? s1 : s2;
  int n0 = blockIdx.x * 32, k0 = blockIdx.y * 32;
  int tx = threadIdx.x & 31, ty = threadIdx.x >> 5;  // 32 x 8
  for (int i = ty; i < 32; i += 8) {
    int k = k0 + i, n = n0 + tx;
    tile[i][tx] = (k < K && n < N) ? src[(size_t)k * N + n] : 0.f;
  }
  __syncthreads();
  for (int i = ty; i < 32; i += 8) {
    int n = n0 + i, k = k0 + tx;
    if (n < Npad && k < K)
      dst[(size_t)p * Npad * K + (size_t)n * K + k] = __float2bfloat16(tile[tx][i]);
  }
}

// ---------- projection GEMM: Y = X[M,K] @ Wt[N,K]^T + bias, scatter to head-layout bf16 ----------
// p = blockIdx.z: 0->qc (scaled), 1->kc, 2->vc
template <int K, int N, int NPAD, int HD, int COFF>
__global__ __launch_bounds__(256, 2) void proj_gemm(
    const __hip_bfloat16* __restrict__ X, const __hip_bfloat16* __restrict__ Wt,
    const float* __restrict__ bq, const float* __restrict__ bk, const float* __restrict__ bv,
    __hip_bfloat16* __restrict__ qc, __hip_bfloat16* __restrict__ kc,
    __hip_bfloat16* __restrict__ vc, float qscale) {
  __shared__ __hip_bfloat16 lA[128 * 32];
  __shared__ __hip_bfloat16 lB[128 * 32];
  const int tid = threadIdx.x, w = tid >> 6, l = tid & 63;
  const int lr = l & 15, lg = l >> 4;
  const int p = blockIdx.z;
  const int m0 = blockIdx.x * 128, n0 = blockIdx.y * 128;
  const __hip_bfloat16* Wp = Wt + (size_t)p * NPAD * K;
  const float* bias = (p == 0) ? bq : (p == 1) ? bk : bv;
  const float scale = (p == 0) ? qscale : 1.0f;

  f32x4 acc[4][4] = {};

  // staging geometry: wave w covers rows [w*32, w*32+16) and [w*32+16, +16); lane 16B
  const int srow = (w * 2) * 16 + (l >> 2);
  const int scol = (l & 3) * 8;
  const __hip_bfloat16* gA = X + (size_t)(m0 + srow) * K + scol;
  const __hip_bfloat16* gB = Wp + (size_t)(n0 + srow) * K + scol;
  __hip_bfloat16* dA = lA + (w * 2) * 512;  // wave-uniform LDS base
  __hip_bfloat16* dB = lB + (w * 2) * 512;
  const int wr = w >> 1, wc = w & 1;

  for (int kk = 0; kk < K; kk += 32) {
    gload16(gA + kk, dA);
    gload16(gA + (size_t)16 * K + kk, dA + 512);
    gload16(gB + kk, dB);
    gload16(gB + (size_t)16 * K + kk, dB + 512);
    __syncthreads();
    bf16x8 af[4], bf[4];
#pragma unroll
    for (int i = 0; i < 4; i++) af[i] = *(const bf16x8*)(lA + (wr * 64 + i * 16 + lr) * 32 + lg * 8);
#pragma unroll
    for (int j = 0; j < 4; j++) bf[j] = *(const bf16x8*)(lB + (wc * 64 + j * 16 + lr) * 32 + lg * 8);
#pragma unroll
    for (int i = 0; i < 4; i++)
#pragma unroll
      for (int j = 0; j < 4; j++) acc[i][j] = MFMA16(af[i], bf[j], acc[i][j]);
    __syncthreads();
  }

#pragma unroll
  for (int j = 0; j < 4; j++) {
    int n = n0 + wc * 64 + j * 16 + lr;
    if (NPAD > N && n >= N) continue;
    float bv_ = bias[n];
    int hh = n / HD, d = n % HD;
#pragma unroll
    for (int i = 0; i < 4; i++) {
#pragma unroll
      for (int r = 0; r < 4; r++) {
        int m = m0 + wr * 64 + i * 16 + lg * 4 + r;
        int bb = m >> 11, s = m & 2047;
        float val = (acc[i][j][r] + bv_) * scale;
        size_t base = (size_t)(bb * 12 + hh) * 2048 + s;
        if (p == 2)      vc[base * 80 + COFF + d] = __float2bfloat16(val);
        else if (p == 1) kc[base * 96 + COFF + d] = __float2bfloat16(val);
        else             qc[base * 96 + COFF + d] = __float2bfloat16(val);
      }
    }
  }
}

// ---------- transpose vc [bh][2048][80] -> vt [bh][80][2048] ----------
__global__ __launch_bounds__(256) void transpose_v(const __hip_bfloat16* __restrict__ vc,
                                                   __hip_bfloat16* __restrict__ vt) {
  __shared__ __hip_bfloat16 t[32][34];
  int bh = blockIdx.z;
  int s0 = blockIdx.x * 32, d0 = blockIdx.y * 32;
  int tx = threadIdx.x & 31, ty = threadIdx.x >> 5;
  for (int i = ty; i < 32; i += 8) {
    int d = d0 + tx;
    if (d < 80) t[i][tx] = vc[((size_t)bh * 2048 + s0 + i) * 80 + d];
  }
  __syncthreads();
  for (int i = ty; i < 32; i += 8) {
    int d = d0 + i;
    if (d < 80) vt[((size_t)bh * 80 + d) * 2048 + s0 + tx] = t[tx][i];
  }
}

// ---------- fused flash attention (shared softmax for both streams) ----------
// qc/kc: [bh][2048][96] bf16 (pre-scaled q, zero pad 80..95); vt: [bh][80][2048] bf16
__global__ __launch_bounds__(256, 2) void attn_kernel(
    const __hip_bfloat16* __restrict__ qc, const __hip_bfloat16* __restrict__ kc,
    const __hip_bfloat16* __restrict__ vt, const float* __restrict__ mask,
    float* __restrict__ out, float* __restrict__ out2) {
  constexpr int KP = 104;  // 96 + 8 pad
  constexpr int VP = 72;   // 64 + 8 pad
  constexpr int SP = 72;   // 64 + 8 pad
  __shared__ __hip_bfloat16 lK[64 * KP];
  __shared__ __hip_bfloat16 lV[80 * VP];
  __shared__ __hip_bfloat16 lP[4 * 16 * SP];
  const int tid = threadIdx.x, w = tid >> 6, l = tid & 63;
  const int lr = l & 15, lg = l >> 4;
  const int bh = blockIdx.y, b_ = bh / 12, h = bh - b_ * 12;
  const int q0 = blockIdx.x * 64;

  // Q fragments held in registers for the whole block (16 rows/wave, K=96)
  bf16x8 aq[3];
  {
    const __hip_bfloat16* qrow = qc + ((size_t)bh * 2048 + q0 + w * 16 + lr) * 96 + lg * 8;
    aq[0] = *(const bf16x8*)(qrow);
    aq[1] = *(const bf16x8*)(qrow + 32);
    aq[2] = *(const bf16x8*)(qrow + 64);
  }
  float mrun[4] = {-INFINITY, -INFINITY, -INFINITY, -INFINITY};
  float lrun[4] = {0.f, 0.f, 0.f, 0.f};
  f32x4 o[5] = {};
  const float* maskb = mask + b_ * 2048;
  __hip_bfloat16* SPw = lP + w * 16 * SP;

  const int krow = tid >> 2, kseg = tid & 3;
  const __hip_bfloat16* kbase = kc + ((size_t)bh * 2048 + krow) * 96 + kseg * 24;
  __hip_bfloat16* kdst = lK + krow * KP + kseg * 24;
  const __hip_bfloat16* vbase = vt + (size_t)bh * 80 * 2048;

  for (int kt = 0; kt < 32; ++kt) {
    const int kv0 = kt * 64;
    {  // stage K tile [64][96] -> lK padded
      const __hip_bfloat16* s = kbase + (size_t)kv0 * 96;
      *(bf16x8*)(kdst) = *(const bf16x8*)(s);
      *(bf16x8*)(kdst + 8) = *(const bf16x8*)(s + 8);
      *(bf16x8*)(kdst + 16) = *(const bf16x8*)(s + 16);
    }
#pragma unroll
    for (int it = 0; it < 3; ++it) {  // stage V^T tile [80][64] -> lV padded
      int idx = tid + it * 256;
      if (idx < 640) {
        int d = idx >> 3, c = idx & 7;
        *(bf16x8*)(lV + d * VP + c * 8) = *(const bf16x8*)(vbase + (size_t)d * 2048 + kv0 + c * 8);
      }
    }
    __syncthreads();

    // S[16 x 64] = qc · kc^T  (combined, pre-scaled scores)
    f32x4 sf[4] = {};
#pragma unroll
    for (int f = 0; f < 4; ++f)
#pragma unroll
      for (int t = 0; t < 3; ++t) {
        bf16x8 bk_ = *(const bf16x8*)(lK + (f * 16 + lr) * KP + t * 32 + lg * 8);
        sf[f] = MFMA16(aq[t], bk_, sf[f]);
      }
    // + mask (per-key bias)
#pragma unroll
    for (int f = 0; f < 4; ++f) {
      float mv = maskb[kv0 + f * 16 + lr];
#pragma unroll
      for (int j = 0; j < 4; j++) sf[f][j] += mv;
    }
    // online softmax; row r = lg*4 + j, cols spread over 16-lane group + 4 frags
    float alpha[4];
#pragma unroll
    for (int j = 0; j < 4; j++) {
      float tm = fmaxf(fmaxf(sf[0][j], sf[1][j]), fmaxf(sf[2][j], sf[3][j]));
#pragma unroll
      for (int d = 1; d < 16; d <<= 1) tm = fmaxf(tm, __shfl_xor(tm, d));
      float nm = fmaxf(mrun[j], tm);
      alpha[j] = __expf(mrun[j] - nm);
      float ps = 0.f;
#pragma unroll
      for (int f = 0; f < 4; f++) {
        float pv = __expf(sf[f][j] - nm);
        sf[f][j] = pv;
        ps += pv;
      }
#pragma unroll
      for (int d = 1; d < 16; d <<= 1) ps += __shfl_xor(ps, d);
      lrun[j] = lrun[j] * alpha[j] + ps;
      mrun[j] = nm;
    }
#pragma unroll
    for (int c = 0; c < 5; c++)
#pragma unroll
      for (int j = 0; j < 4; j++) o[c][j] *= alpha[j];

    // stash P (bf16) to per-wave LDS to re-layout D->A operand
#pragma unroll
    for (int f = 0; f < 4; f++)
#pragma unroll
      for (int j = 0; j < 4; j++)
        SPw[(lg * 4 + j) * SP + f * 16 + lr] = __float2bfloat16(sf[f][j]);
    __syncthreads();  // conservative: cross-lane LDS visibility (optimize later)

    // O[16 x 80] += P · V
#pragma unroll
    for (int t2 = 0; t2 < 2; t2++) {
      bf16x8 pa = *(const bf16x8*)(SPw + lr * SP + t2 * 32 + lg * 8);
#pragma unroll
      for (int c = 0; c < 5; c++) {
        bf16x8 bv_ = *(const bf16x8*)(lV + (c * 16 + lr) * VP + t2 * 32 + lg * 8);
        o[c] = MFMA16(pa, bv_, o[c]);
      }
    }
    __syncthreads();  // protect lK/lV before next stage
  }

  float inv[4];
#pragma unroll
  for (int j = 0; j < 4; j++) inv[j] = 1.0f / lrun[j];
#pragma unroll
  for (int c = 0; c < 5; c++) {
#pragma unroll
    for (int j = 0; j < 4; j++) {
      int qg = q0 + w * 16 + lg * 4 + j;
      float val = o[c][j] * inv[j];
      if (c < 4) out[((size_t)b_ * 2048 + qg) * 768 + h * 64 + c * 16 + lr] = val;
      else       out2[((size_t)b_ * 2048 + qg) * 192 + h * 16 + lr] = val;
    }
  }
}

// ---------- launch ----------
extern "C" void kernel_launch(void* const* d_in, const int* in_sizes, int n_in,
                              void* d_out, int out_size, void* d_ws, size_t ws_size,
                              hipStream_t stream) {
  const float* hidden = (const float*)d_in[0];
  const float* lhidden = (const float*)d_in[1];
  const float* mask = (const float*)d_in[2];
  const float* Wq = (const float*)d_in[3];
  const float* bq = (const float*)d_in[4];
  const float* Wk = (const float*)d_in[5];
  const float* bk = (const float*)d_in[6];
  const float* Wv = (const float*)d_in[7];
  const float* bv = (const float*)d_in[8];
  const float* LWq = (const float*)d_in[9];
  const float* Lbq = (const float*)d_in[10];
  const float* LWk = (const float*)d_in[11];
  const float* Lbk = (const float*)d_in[12];
  const float* LWv = (const float*)d_in[13];
  const float* Lbv = (const float*)d_in[14];

  char* ws = (char*)d_ws;
  __hip_bfloat16* Xb  = (__hip_bfloat16*)(ws + 0);          // 12582912 B
  __hip_bfloat16* LXb = (__hip_bfloat16*)(ws + 12582912);   //  3145728 B
  __hip_bfloat16* Wt  = (__hip_bfloat16*)(ws + 15728640);   //  3538944 B
  __hip_bfloat16* LWt = (__hip_bfloat16*)(ws + 19267584);   //   294912 B
  __hip_bfloat16* qcb = (__hip_bfloat16*)(ws + 19562496);   // 18874368 B
  __hip_bfloat16* kcb = (__hip_bfloat16*)(ws + 38436864);   // 18874368 B
  __hip_bfloat16* vcb = (__hip_bfloat16*)(ws + 57311232);   // 15728640 B
  __hip_bfloat16* vtb = (__hip_bfloat16*)(ws + 73039872);   // 15728640 B  (total 88768512)

  float* out = (float*)d_out;
  float* out2 = out + (size_t)4 * 2048 * 768;

  // zero qc+kc (contiguous) so the 80..95 pad columns are 0
  hipMemsetAsync(qcb, 0, (size_t)2 * 18874368, stream);

  cvt_f32_bf16<<<2048, 256, 0, stream>>>(hidden, Xb, 6291456);
  cvt_f32_bf16<<<1024, 256, 0, stream>>>(lhidden, LXb, 1572864);
  transpose_cvt<<<dim3(24, 24, 3), 256, 0, stream>>>(Wq, Wk, Wv, Wt, 768, 768, 768);
  transpose_cvt<<<dim3(8, 6, 3), 256, 0, stream>>>(LWq, LWk, LWv, LWt, 192, 192, 256);

  proj_gemm<768, 768, 768, 64, 0><<<dim3(64, 6, 3), 256, 0, stream>>>(
      Xb, Wt, bq, bk, bv, qcb, kcb, vcb, 0.125f);
  proj_gemm<192, 192, 256, 16, 64><<<dim3(64, 2, 3), 256, 0, stream>>>(
      LXb, LWt, Lbq, Lbk, Lbv, qcb, kcb, vcb, 0.25f);

  transpose_v<<<dim3(64, 3, 48), 256, 0, stream>>>(vcb, vtb);
  attn_kernel<<<dim3(32, 48), 256, 0, stream>>>(qcb, kcb, vtb, mask, out, out2);
}

// Round 3
// 338.032 us; speedup vs baseline: 1.2624x; 1.2624x over previous
//
#include <hip/hip_runtime.h>
#include <hip/hip_bf16.h>
#include <cstdint>

// ---------- types / helpers ----------
typedef __attribute__((ext_vector_type(8))) short bf16x8;   // 8 bf16 in 4 VGPRs
typedef __attribute__((ext_vector_type(4))) float f32x4;

#define MFMA16(a, b, c) __builtin_amdgcn_mfma_f32_16x16x32_bf16((a), (b), (c), 0, 0, 0)

static __device__ __forceinline__ unsigned short f2b(float x) {
  __hip_bfloat16 h = __float2bfloat16(x);
  return __builtin_bit_cast(unsigned short, h);
}

// ---------- f32 -> bf16 elementwise convert ----------
__global__ __launch_bounds__(256) void cvt_f32_bf16(const float* __restrict__ s,
                                                    __hip_bfloat16* __restrict__ d, int n) {
  int stride = gridDim.x * 256 * 4;
  for (int i = (blockIdx.x * 256 + threadIdx.x) * 4; i < n; i += stride) {
    float4 v = *(const float4*)(s + i);
    ushort4 o;
    o.x = f2b(v.x); o.y = f2b(v.y); o.z = f2b(v.z); o.w = f2b(v.w);
    *(ushort4*)&d[i] = o;
  }
}

// ---------- transpose-convert weights: dst[p][n][k] = (bf16) src_p[k][n], zero pad n in [N,Npad) ----------
__global__ __launch_bounds__(256) void transpose_cvt(const float* __restrict__ s0,
                                                     const float* __restrict__ s1,
                                                     const float* __restrict__ s2,
                                                     __hip_bfloat16* __restrict__ dst,
                                                     int K, int N, int Npad) {
  __shared__ float tile[32][33];
  int p = blockIdx.z;
  const float* src = (p == 0) ? s0 : (p == 1) ? s1 : s2;
  int n0 = blockIdx.x * 32, k0 = blockIdx.y * 32;
  int tx = threadIdx.x & 31, ty = threadIdx.x >> 5;  // 32 x 8
  for (int i = ty; i < 32; i += 8) {
    int k = k0 + i, n = n0 + tx;
    tile[i][tx] = (k < K && n < N) ? src[(size_t)k * N + n] : 0.f;
  }
  __syncthreads();
  for (int i = ty; i < 32; i += 8) {
    int n = n0 + i, k = k0 + tx;
    if (n < Npad && k < K)
      dst[(size_t)p * Npad * K + (size_t)n * K + k] = __float2bfloat16(tile[tx][i]);
  }
}

// ---------- projection GEMM: Y = X[M,K] @ Wt[N,K]^T + bias, scatter to head-layout bf16 ----------
// computes C^T via swapped MFMA operands so stores are 4-wide along n (b64)
template <int K, int N, int NPAD, int HD, int COFF>
__global__ __launch_bounds__(256, 2) void proj_gemm(
    const __hip_bfloat16* __restrict__ X, const __hip_bfloat16* __restrict__ Wt,
    const float* __restrict__ bq, const float* __restrict__ bk, const float* __restrict__ bv,
    __hip_bfloat16* __restrict__ qc, __hip_bfloat16* __restrict__ kc,
    __hip_bfloat16* __restrict__ vc, float qscale) {
  __shared__ __hip_bfloat16 lA[128 * 32];
  __shared__ __hip_bfloat16 lB[128 * 32];
  const int tid = threadIdx.x, w = tid >> 6, l = tid & 63;
  const int lr = l & 15, lg = l >> 4;
  const int p = blockIdx.z;
  const int m0 = blockIdx.x * 128, n0 = blockIdx.y * 128;
  const __hip_bfloat16* Wp = Wt + (size_t)p * NPAD * K;
  const float* bias = (p == 0) ? bq : (p == 1) ? bk : bv;
  const float scale = (p == 0) ? qscale : 1.0f;
  __hip_bfloat16* dstb = (p == 0) ? qc : (p == 1) ? kc : vc;

  f32x4 acc[4][4] = {};

  const int srow = (w * 2) * 16 + (l >> 2);
  const int scol = (l & 3) * 8;
  const __hip_bfloat16* gA = X + (size_t)(m0 + srow) * K + scol;
  const __hip_bfloat16* gB = Wp + (size_t)(n0 + srow) * K + scol;
  __hip_bfloat16* dA = lA + (w * 2) * 512;  // wave-uniform LDS base
  __hip_bfloat16* dB = lB + (w * 2) * 512;
  const int wr = w >> 1, wc = w & 1;

  for (int kk = 0; kk < K; kk += 32) {
    __builtin_amdgcn_global_load_lds((const __attribute__((address_space(1))) void*)(gA + kk),
                                     (__attribute__((address_space(3))) void*)dA, 16, 0, 0);
    __builtin_amdgcn_global_load_lds((const __attribute__((address_space(1))) void*)(gA + (size_t)16 * K + kk),
                                     (__attribute__((address_space(3))) void*)(dA + 512), 16, 0, 0);
    __builtin_amdgcn_global_load_lds((const __attribute__((address_space(1))) void*)(gB + kk),
                                     (__attribute__((address_space(3))) void*)dB, 16, 0, 0);
    __builtin_amdgcn_global_load_lds((const __attribute__((address_space(1))) void*)(gB + (size_t)16 * K + kk),
                                     (__attribute__((address_space(3))) void*)(dB + 512), 16, 0, 0);
    __syncthreads();
    bf16x8 af[4], bfr[4];
#pragma unroll
    for (int i = 0; i < 4; i++) af[i] = *(const bf16x8*)(lA + (wr * 64 + i * 16 + lr) * 32 + lg * 8);
#pragma unroll
    for (int j = 0; j < 4; j++) bfr[j] = *(const bf16x8*)(lB + (wc * 64 + j * 16 + lr) * 32 + lg * 8);
#pragma unroll
    for (int i = 0; i < 4; i++)
#pragma unroll
      for (int j = 0; j < 4; j++) acc[i][j] = MFMA16(bfr[j], af[i], acc[i][j]);  // C^T
    __syncthreads();
  }

  // epilogue: thread owns 4 consecutive n (regs) x 16 m (lr) per (i,j)
#pragma unroll
  for (int j = 0; j < 4; j++) {
    int nb = n0 + wc * 64 + j * 16 + lg * 4;
    if (NPAD > N && nb >= N) continue;
    float4 bv4 = *(const float4*)(bias + nb);
    int hh = nb / HD, d0 = nb % HD;
#pragma unroll
    for (int i = 0; i < 4; i++) {
      int m = m0 + wr * 64 + i * 16 + lr;
      int bb = m >> 11, s = m & 2047;
      size_t base = ((size_t)(bb * 12 + hh) * 2048 + s) * 80 + COFF + d0;
      ushort4 st;
      st.x = f2b((acc[i][j][0] + bv4.x) * scale);
      st.y = f2b((acc[i][j][1] + bv4.y) * scale);
      st.z = f2b((acc[i][j][2] + bv4.z) * scale);
      st.w = f2b((acc[i][j][3] + bv4.w) * scale);
      *(ushort4*)(dstb + base) = st;
    }
  }
}

// ---------- transpose vc [bh][2048][80] -> vt [bh][80][2048] ----------
__global__ __launch_bounds__(256) void transpose_v(const __hip_bfloat16* __restrict__ vc,
                                                   __hip_bfloat16* __restrict__ vt) {
  __shared__ __hip_bfloat16 t[32][34];
  int bh = blockIdx.z;
  int s0 = blockIdx.x * 32, d0 = blockIdx.y * 32;
  int tx = threadIdx.x & 31, ty = threadIdx.x >> 5;
  for (int i = ty; i < 32; i += 8) {
    int d = d0 + tx;
    if (d < 80) t[i][tx] = vc[((size_t)bh * 2048 + s0 + i) * 80 + d];
  }
  __syncthreads();
  for (int i = ty; i < 32; i += 8) {
    int d = d0 + i;
    if (d < 80) vt[((size_t)bh * 80 + d) * 2048 + s0 + tx] = t[tx][i];
  }
}

// ---------- fused flash attention (shared softmax, ones-column denominator) ----------
// qc/kc: [bh][2048][80] bf16 (q pre-scaled); vt: [bh][80][2048] bf16
__global__ __launch_bounds__(256, 3) void attn_kernel(
    const __hip_bfloat16* __restrict__ qc, const __hip_bfloat16* __restrict__ kc,
    const __hip_bfloat16* __restrict__ vt, const float* __restrict__ mask,
    float* __restrict__ out, float* __restrict__ out2) {
  constexpr int KP = 88;   // 80 data + 8 pad: 2-way banks on b128 reads
  constexpr int VP = 72;   // 64 data + 8 pad
  constexpr int SP = 72;
  __shared__ __hip_bfloat16 lK[64 * KP];      // K tile
  __shared__ __hip_bfloat16 lV[96 * VP];      // V^T rows 0..79; row 80 = ones; 81..95 = 0
  __shared__ __hip_bfloat16 lP[4 * 32 * SP];  // per-wave P stash (32 q-rows)
  const int tid = threadIdx.x, w = tid >> 6, l = tid & 63;
  const int lr = l & 15, lg = l >> 4;
  const int bh = blockIdx.y, b_ = bh / 12, h = bh - b_ * 12;
  const int q0 = blockIdx.x * 128;

  // --- per-thread staging slots: K tile = 640 b128 chunks, V tile = 640 ---
  const __hip_bfloat16* gsrc[5];
  int gstep[5];
  __hip_bfloat16* ldst[5];
#pragma unroll
  for (int s = 0; s < 5; ++s) {
    int idx = tid + s * 256;
    if (idx < 640) {
      int r = idx / 10, c = idx - r * 10;
      gsrc[s] = kc + ((size_t)bh * 2048 + r) * 80 + c * 8;
      gstep[s] = 64 * 80;
      ldst[s] = lK + r * KP + c * 8;
    } else {
      int vi = idx - 640;
      int r = vi >> 3, c = vi & 7;
      gsrc[s] = vt + ((size_t)bh * 80 + r) * 2048 + c * 8;
      gstep[s] = 64;
      ldst[s] = lV + r * VP + c * 8;
    }
  }

  // --- Q in registers: 2 groups x 16 rows; k 64..79 tail via zeroed lanes lg>=2 ---
  const bf16x8 zz = {0, 0, 0, 0, 0, 0, 0, 0};
  bf16x8 aq[2][3];
#pragma unroll
  for (int g = 0; g < 2; ++g) {
    const __hip_bfloat16* qrow = qc + ((size_t)bh * 2048 + q0 + w * 32 + g * 16 + lr) * 80;
    aq[g][0] = *(const bf16x8*)(qrow + lg * 8);
    aq[g][1] = *(const bf16x8*)(qrow + 32 + lg * 8);
    bf16x8 t = *(const bf16x8*)(qrow + 64 + (lg & 1) * 8);
    aq[g][2] = (lg < 2) ? t : zz;
  }

  // --- prologue: ones/zero rows of lV, stage tile 0 ---
  if (tid < 128) {
    int r = 80 + (tid >> 3), c = tid & 7;
    short v = (r == 80) ? (short)0x3F80 : (short)0;
    bf16x8 x = {v, v, v, v, v, v, v, v};
    *(bf16x8*)(lV + r * VP + c * 8) = x;
  }
  {
    bf16x8 r0[5];
#pragma unroll
    for (int s = 0; s < 5; ++s) r0[s] = *(const bf16x8*)(gsrc[s]);
#pragma unroll
    for (int s = 0; s < 5; ++s) *(bf16x8*)(ldst[s]) = r0[s];
  }
  __syncthreads();

  float mrun[2][4];
#pragma unroll
  for (int g = 0; g < 2; ++g)
#pragma unroll
    for (int j = 0; j < 4; ++j) mrun[g][j] = -INFINITY;
  f32x4 o[2][6] = {};
  const float* maskb = mask + b_ * 2048;
  __hip_bfloat16* SPw = lP + w * 32 * SP;

  for (int kt = 0; kt < 32; ++kt) {
    // T14: issue next-tile global loads early; write to LDS after compute barrier
    int ktn = (kt + 1 < 32) ? kt + 1 : 31;
    bf16x8 pre[5];
#pragma unroll
    for (int s = 0; s < 5; ++s)
      pre[s] = *(const bf16x8*)(gsrc[s] + (size_t)ktn * gstep[s]);

    const int kv0 = kt * 64;
    float alpha[2][4];
#pragma unroll
    for (int g = 0; g < 2; ++g) {
      f32x4 sf[4] = {};
#pragma unroll
      for (int f = 0; f < 4; ++f) {
        const __hip_bfloat16* kr = lK + (f * 16 + lr) * KP;
        bf16x8 b0 = *(const bf16x8*)(kr + lg * 8);
        bf16x8 b1 = *(const bf16x8*)(kr + 32 + lg * 8);
        bf16x8 bt = *(const bf16x8*)(kr + 64 + (lg & 1) * 8);
        bf16x8 b2 = (lg < 2) ? bt : zz;
        sf[f] = MFMA16(aq[g][0], b0, sf[f]);
        sf[f] = MFMA16(aq[g][1], b1, sf[f]);
        sf[f] = MFMA16(aq[g][2], b2, sf[f]);
      }
#pragma unroll
      for (int f = 0; f < 4; ++f) {
        float mv = maskb[kv0 + f * 16 + lr];
#pragma unroll
        for (int j = 0; j < 4; ++j) sf[f][j] += mv;
      }
      // online max (sum comes free from the ones-column in PV)
#pragma unroll
      for (int j = 0; j < 4; ++j) {
        float tm = fmaxf(fmaxf(sf[0][j], sf[1][j]), fmaxf(sf[2][j], sf[3][j]));
#pragma unroll
        for (int d = 1; d < 16; d <<= 1) tm = fmaxf(tm, __shfl_xor(tm, d));
        float nm = fmaxf(mrun[g][j], tm);
        alpha[g][j] = __expf(mrun[g][j] - nm);
        mrun[g][j] = nm;
#pragma unroll
        for (int f = 0; f < 4; ++f) sf[f][j] = __expf(sf[f][j] - nm);
      }
      // stash P rows g*16 + lg*4 + j (wave-private: no barrier needed)
#pragma unroll
      for (int f = 0; f < 4; ++f)
#pragma unroll
        for (int j = 0; j < 4; ++j)
          SPw[(g * 16 + lg * 4 + j) * SP + f * 16 + lr] = __float2bfloat16(sf[f][j]);
    }
    // rescale O (incl. denominator frag c=5)
#pragma unroll
    for (int g = 0; g < 2; ++g)
#pragma unroll
      for (int c = 0; c < 6; ++c)
#pragma unroll
        for (int j = 0; j < 4; ++j) o[g][c][j] *= alpha[g][j];

    // PV merged over both q-groups (V frags read once)
#pragma unroll
    for (int t2 = 0; t2 < 2; ++t2) {
      bf16x8 pa0 = *(const bf16x8*)(SPw + lr * SP + t2 * 32 + lg * 8);
      bf16x8 pa1 = *(const bf16x8*)(SPw + (16 + lr) * SP + t2 * 32 + lg * 8);
#pragma unroll
      for (int c = 0; c < 6; ++c) {
        bf16x8 bv_ = *(const bf16x8*)(lV + (c * 16 + lr) * VP + t2 * 32 + lg * 8);
        o[0][c] = MFMA16(pa0, bv_, o[0][c]);
        o[1][c] = MFMA16(pa1, bv_, o[1][c]);
      }
    }
    __syncthreads();
#pragma unroll
    for (int s = 0; s < 5; ++s) *(bf16x8*)(ldst[s]) = pre[s];
    __syncthreads();
  }

  // epilogue: denominator = ones-column (col 80 -> lane lr==0 of each 16-group)
#pragma unroll
  for (int g = 0; g < 2; ++g) {
#pragma unroll
    for (int j = 0; j < 4; ++j) {
      float den = __shfl(o[g][5][j], (l & 48));
      float inv = 1.0f / den;
      int qg = q0 + w * 32 + g * 16 + lg * 4 + j;
      float* ob = out + ((size_t)b_ * 2048 + qg) * 768 + h * 64;
#pragma unroll
      for (int c = 0; c < 4; ++c) ob[c * 16 + lr] = o[g][c][j] * inv;
      out2[((size_t)b_ * 2048 + qg) * 192 + h * 16 + lr] = o[g][4][j] * inv;
    }
  }
}

// ---------- launch ----------
extern "C" void kernel_launch(void* const* d_in, const int* in_sizes, int n_in,
                              void* d_out, int out_size, void* d_ws, size_t ws_size,
                              hipStream_t stream) {
  const float* hidden = (const float*)d_in[0];
  const float* lhidden = (const float*)d_in[1];
  const float* mask = (const float*)d_in[2];
  const float* Wq = (const float*)d_in[3];
  const float* bq = (const float*)d_in[4];
  const float* Wk = (const float*)d_in[5];
  const float* bk = (const float*)d_in[6];
  const float* Wv = (const float*)d_in[7];
  const float* bv = (const float*)d_in[8];
  const float* LWq = (const float*)d_in[9];
  const float* Lbq = (const float*)d_in[10];
  const float* LWk = (const float*)d_in[11];
  const float* Lbk = (const float*)d_in[12];
  const float* LWv = (const float*)d_in[13];
  const float* Lbv = (const float*)d_in[14];

  char* ws = (char*)d_ws;
  __hip_bfloat16* Xb  = (__hip_bfloat16*)(ws + 0);          // 12582912 B
  __hip_bfloat16* LXb = (__hip_bfloat16*)(ws + 12582912);   //  3145728 B
  __hip_bfloat16* Wt  = (__hip_bfloat16*)(ws + 15728640);   //  3538944 B
  __hip_bfloat16* LWt = (__hip_bfloat16*)(ws + 19267584);   //   294912 B
  __hip_bfloat16* qcb = (__hip_bfloat16*)(ws + 19562496);   // 15728640 B
  __hip_bfloat16* kcb = (__hip_bfloat16*)(ws + 35291136);   // 15728640 B
  __hip_bfloat16* vcb = (__hip_bfloat16*)(ws + 51019776);   // 15728640 B
  __hip_bfloat16* vtb = (__hip_bfloat16*)(ws + 66748416);   // 15728640 B  (end 82477056)

  float* out = (float*)d_out;
  float* out2 = out + (size_t)4 * 2048 * 768;

  cvt_f32_bf16<<<2048, 256, 0, stream>>>(hidden, Xb, 6291456);
  cvt_f32_bf16<<<1024, 256, 0, stream>>>(lhidden, LXb, 1572864);
  transpose_cvt<<<dim3(24, 24, 3), 256, 0, stream>>>(Wq, Wk, Wv, Wt, 768, 768, 768);
  transpose_cvt<<<dim3(8, 6, 3), 256, 0, stream>>>(LWq, LWk, LWv, LWt, 192, 192, 256);

  proj_gemm<768, 768, 768, 64, 0><<<dim3(64, 6, 3), 256, 0, stream>>>(
      Xb, Wt, bq, bk, bv, qcb, kcb, vcb, 0.125f);
  proj_gemm<192, 192, 256, 16, 64><<<dim3(64, 2, 3), 256, 0, stream>>>(
      LXb, LWt, Lbq, Lbk, Lbv, qcb, kcb, vcb, 0.25f);

  transpose_v<<<dim3(64, 3, 48), 256, 0, stream>>>(vcb, vtb);
  attn_kernel<<<dim3(16, 48), 256, 0, stream>>>(qcb, kcb, vtb, mask, out, out2);
}

// Round 4
// 319.670 us; speedup vs baseline: 1.3349x; 1.0574x over previous
//
#include <hip/hip_runtime.h>
#include <hip/hip_bf16.h>
#include <cstdint>
#include <math.h>

// ---------- types / helpers ----------
typedef __attribute__((ext_vector_type(8))) short bf16x8;   // 8 bf16 in 4 VGPRs
typedef __attribute__((ext_vector_type(4))) float f32x4;

#define MFMA16(a, b, c) __builtin_amdgcn_mfma_f32_16x16x32_bf16((a), (b), (c), 0, 0, 0)
// MFMA16(A,B,C): D col(lane&15) = B's row index, D row((lane>>4)*4+reg) = A's row index.

static __device__ __forceinline__ unsigned short f2b(float x) {
  __hip_bfloat16 h = __float2bfloat16(x);
  return __builtin_bit_cast(unsigned short, h);
}

#define INVLN2 1.4426950408889634f

// ---------- f32 -> bf16 elementwise convert ----------
__global__ __launch_bounds__(256) void cvt_f32_bf16(const float* __restrict__ s,
                                                    __hip_bfloat16* __restrict__ d, int n) {
  int stride = gridDim.x * 256 * 4;
  for (int i = (blockIdx.x * 256 + threadIdx.x) * 4; i < n; i += stride) {
    float4 v = *(const float4*)(s + i);
    ushort4 o;
    o.x = f2b(v.x); o.y = f2b(v.y); o.z = f2b(v.z); o.w = f2b(v.w);
    *(ushort4*)&d[i] = o;
  }
}

// ---------- transpose-convert weights: dst[p][n][k] = (bf16) src_p[k][n], zero pad n in [N,Npad) ----------
__global__ __launch_bounds__(256) void transpose_cvt(const float* __restrict__ s0,
                                                     const float* __restrict__ s1,
                                                     const float* __restrict__ s2,
                                                     __hip_bfloat16* __restrict__ dst,
                                                     int K, int N, int Npad) {
  __shared__ float tile[32][33];
  int p = blockIdx.z;
  const float* src = (p == 0) ? s0 : (p == 1) ? s1 : s2;
  int n0 = blockIdx.x * 32, k0 = blockIdx.y * 32;
  int tx = threadIdx.x & 31, ty = threadIdx.x >> 5;  // 32 x 8
  for (int i = ty; i < 32; i += 8) {
    int k = k0 + i, n = n0 + tx;
    tile[i][tx] = (k < K && n < N) ? src[(size_t)k * N + n] : 0.f;
  }
  __syncthreads();
  for (int i = ty; i < 32; i += 8) {
    int n = n0 + i, k = k0 + tx;
    if (n < Npad && k < K)
      dst[(size_t)p * Npad * K + (size_t)n * K + k] = __float2bfloat16(tile[tx][i]);
  }
}

// ---------- projection GEMM: Y = X[M,K] @ Wt[N,K]^T + bias ----------
// computes C^T via swapped MFMA operands; p=0 -> qc (scaled), p=1 -> kc, p=2 -> vt (direct-transposed)
template <int K, int N, int NPAD, int HD, int COFF>
__global__ __launch_bounds__(256, 2) void proj_gemm(
    const __hip_bfloat16* __restrict__ X, const __hip_bfloat16* __restrict__ Wt,
    const float* __restrict__ bq, const float* __restrict__ bk, const float* __restrict__ bv,
    __hip_bfloat16* __restrict__ qc, __hip_bfloat16* __restrict__ kc,
    __hip_bfloat16* __restrict__ vt, float qscale) {
  __shared__ __hip_bfloat16 lA[128 * 32];
  __shared__ __hip_bfloat16 lB[128 * 32];
  const int tid = threadIdx.x, w = tid >> 6, l = tid & 63;
  const int lr = l & 15, lg = l >> 4;
  const int p = blockIdx.z;
  const int m0 = blockIdx.x * 128, n0 = blockIdx.y * 128;
  const __hip_bfloat16* Wp = Wt + (size_t)p * NPAD * K;
  const float* bias = (p == 0) ? bq : (p == 1) ? bk : bv;
  const float scale = (p == 0) ? qscale : 1.0f;

  f32x4 acc[4][4] = {};

  const int srow = (w * 2) * 16 + (l >> 2);
  const int scol = (l & 3) * 8;
  const __hip_bfloat16* gA = X + (size_t)(m0 + srow) * K + scol;
  const __hip_bfloat16* gB = Wp + (size_t)(n0 + srow) * K + scol;
  __hip_bfloat16* dA = lA + (w * 2) * 512;  // wave-uniform LDS base
  __hip_bfloat16* dB = lB + (w * 2) * 512;
  const int wr = w >> 1, wc = w & 1;

  for (int kk = 0; kk < K; kk += 32) {
    __builtin_amdgcn_global_load_lds((const __attribute__((address_space(1))) void*)(gA + kk),
                                     (__attribute__((address_space(3))) void*)dA, 16, 0, 0);
    __builtin_amdgcn_global_load_lds((const __attribute__((address_space(1))) void*)(gA + (size_t)16 * K + kk),
                                     (__attribute__((address_space(3))) void*)(dA + 512), 16, 0, 0);
    __builtin_amdgcn_global_load_lds((const __attribute__((address_space(1))) void*)(gB + kk),
                                     (__attribute__((address_space(3))) void*)dB, 16, 0, 0);
    __builtin_amdgcn_global_load_lds((const __attribute__((address_space(1))) void*)(gB + (size_t)16 * K + kk),
                                     (__attribute__((address_space(3))) void*)(dB + 512), 16, 0, 0);
    __syncthreads();
    bf16x8 af[4], bfr[4];
#pragma unroll
    for (int i = 0; i < 4; i++) af[i] = *(const bf16x8*)(lA + (wr * 64 + i * 16 + lr) * 32 + lg * 8);
#pragma unroll
    for (int j = 0; j < 4; j++) bfr[j] = *(const bf16x8*)(lB + (wc * 64 + j * 16 + lr) * 32 + lg * 8);
#pragma unroll
    for (int i = 0; i < 4; i++)
#pragma unroll
      for (int j = 0; j < 4; j++) acc[i][j] = MFMA16(bfr[j], af[i], acc[i][j]);  // C^T
    __syncthreads();
  }

  // epilogue: thread owns 4 consecutive n (regs) x 16 m (lr) per (i,j)
#pragma unroll
  for (int j = 0; j < 4; j++) {
    int nb = n0 + wc * 64 + j * 16 + lg * 4;
    if (NPAD > N && nb >= N) continue;
    float4 bv4 = *(const float4*)(bias + nb);
    int hh = nb / HD, d0 = nb % HD;
#pragma unroll
    for (int i = 0; i < 4; i++) {
      int m = m0 + wr * 64 + i * 16 + lr;
      int bb = m >> 11, s = m & 2047;
      if (p == 2) {
        // direct-transposed V: vt[bh][80][2048]
        size_t based = ((size_t)(bb * 12 + hh) * 80 + COFF + d0) * 2048 + s;
        vt[based]          = __float2bfloat16(acc[i][j][0] + bv4.x);
        vt[based + 2048]   = __float2bfloat16(acc[i][j][1] + bv4.y);
        vt[based + 4096]   = __float2bfloat16(acc[i][j][2] + bv4.z);
        vt[based + 6144]   = __float2bfloat16(acc[i][j][3] + bv4.w);
      } else {
        size_t base = ((size_t)(bb * 12 + hh) * 2048 + s) * 80 + COFF + d0;
        ushort4 st;
        st.x = f2b((acc[i][j][0] + bv4.x) * scale);
        st.y = f2b((acc[i][j][1] + bv4.y) * scale);
        st.z = f2b((acc[i][j][2] + bv4.z) * scale);
        st.w = f2b((acc[i][j][3] + bv4.w) * scale);
        *(ushort4*)((p == 0 ? qc : kc) + base) = st;
      }
    }
  }
}

// ---------- fused flash attention (shared softmax, S^T layout, ones-column denominator) ----------
// qc/kc: [bh][2048][80] bf16 (q pre-scaled by 1/(8 ln2) resp 1/(4 ln2)); vt: [bh][80][2048] bf16
__global__ __launch_bounds__(256, 3) void attn_kernel(
    const __hip_bfloat16* __restrict__ qc, const __hip_bfloat16* __restrict__ kc,
    const __hip_bfloat16* __restrict__ vt, const float* __restrict__ mask,
    float* __restrict__ out, float* __restrict__ out2) {
  constexpr int KP = 88;   // 80 data + 8 pad
  constexpr int VP = 72;   // 64 data + 8 pad
  constexpr int SP = 72;
  __shared__ __hip_bfloat16 lK[64 * KP];      // K tile
  __shared__ __hip_bfloat16 lV[96 * VP];      // V^T rows 0..79; row 80 = ones; 81..95 = 0
  __shared__ __hip_bfloat16 lP[4 * 32 * SP];  // per-wave P stash, [qrow 32][key 64+pad]
  const int tid = threadIdx.x, w = tid >> 6, l = tid & 63;
  const int lr = l & 15, lg = l >> 4;
  const int bh = blockIdx.y, b_ = bh / 12, h = bh - b_ * 12;
  const int q0 = blockIdx.x * 128;

  // --- per-thread staging slots: K tile = 640 b128 chunks, V tile = 640 ---
  const __hip_bfloat16* gsrc[5];
  int gstep[5];
  __hip_bfloat16* ldst[5];
#pragma unroll
  for (int s = 0; s < 5; ++s) {
    int idx = tid + s * 256;
    if (idx < 640) {
      int r = idx / 10, c = idx - r * 10;
      gsrc[s] = kc + ((size_t)bh * 2048 + r) * 80 + c * 8;
      gstep[s] = 64 * 80;
      ldst[s] = lK + r * KP + c * 8;
    } else {
      int vi = idx - 640;
      int r = vi >> 3, c = vi & 7;
      gsrc[s] = vt + ((size_t)bh * 80 + r) * 2048 + c * 8;
      gstep[s] = 64;
      ldst[s] = lV + r * VP + c * 8;
    }
  }

  // --- Q in registers: 2 groups x 16 rows; k 64..79 tail via zeroed lanes lg>=2 ---
  const bf16x8 zz = {0, 0, 0, 0, 0, 0, 0, 0};
  bf16x8 aq[2][3];
#pragma unroll
  for (int g = 0; g < 2; ++g) {
    const __hip_bfloat16* qrow = qc + ((size_t)bh * 2048 + q0 + w * 32 + g * 16 + lr) * 80;
    aq[g][0] = *(const bf16x8*)(qrow + lg * 8);
    aq[g][1] = *(const bf16x8*)(qrow + 32 + lg * 8);
    bf16x8 t = *(const bf16x8*)(qrow + 64 + (lg & 1) * 8);
    aq[g][2] = (lg < 2) ? t : zz;
  }

  // --- prologue: ones/zero rows of lV, stage tile 0 ---
  if (tid < 128) {
    int r = 80 + (tid >> 3), c = tid & 7;
    short v = (r == 80) ? (short)0x3F80 : (short)0;
    bf16x8 x = {v, v, v, v, v, v, v, v};
    *(bf16x8*)(lV + r * VP + c * 8) = x;
  }
  {
    bf16x8 r0[5];
#pragma unroll
    for (int s = 0; s < 5; ++s) r0[s] = *(const bf16x8*)(gsrc[s]);
#pragma unroll
    for (int s = 0; s < 5; ++s) *(bf16x8*)(ldst[s]) = r0[s];
  }
  __syncthreads();

  float mrun[2] = {-INFINITY, -INFINITY};  // per-lane row max (qrow = lr of each group)
  f32x4 o[2][6] = {};
  const float* maskb = mask + b_ * 2048;
  __hip_bfloat16* SPw = lP + w * 32 * SP;

  for (int kt = 0; kt < 32; ++kt) {
    // T14: issue next-tile global loads early; write to LDS after compute barrier
    int ktn = (kt + 1 < 32) ? kt + 1 : 31;
    bf16x8 pre[5];
#pragma unroll
    for (int s = 0; s < 5; ++s)
      pre[s] = *(const bf16x8*)(gsrc[s] + (size_t)ktn * gstep[s]);

    const int kv0 = kt * 64;

    // S^T = K · Q^T : col(lr) = qrow, row(lg*4+r) = key f*16+lg*4+r
    f32x4 sf[2][4] = {};
#pragma unroll
    for (int f = 0; f < 4; ++f) {
      const __hip_bfloat16* kr = lK + (f * 16 + lr) * KP;
      bf16x8 b0 = *(const bf16x8*)(kr + lg * 8);
      bf16x8 b1 = *(const bf16x8*)(kr + 32 + lg * 8);
      bf16x8 bt = *(const bf16x8*)(kr + 64 + (lg & 1) * 8);
      bf16x8 b2 = (lg < 2) ? bt : zz;
#pragma unroll
      for (int g = 0; g < 2; ++g) {
        sf[g][f] = MFMA16(b0, aq[g][0], sf[g][f]);
        sf[g][f] = MFMA16(b1, aq[g][1], sf[g][f]);
        sf[g][f] = MFMA16(b2, aq[g][2], sf[g][f]);
      }
    }
    // + mask (per-key bias, exp2-domain)
#pragma unroll
    for (int f = 0; f < 4; ++f) {
      float4 mv = *(const float4*)(maskb + kv0 + f * 16 + lg * 4);
#pragma unroll
      for (int g = 0; g < 2; ++g) {
        sf[g][f][0] += mv.x * INVLN2;
        sf[g][f][1] += mv.y * INVLN2;
        sf[g][f][2] += mv.z * INVLN2;
        sf[g][f][3] += mv.w * INVLN2;
      }
    }
    // per-lane row max over 16 keys, then 2-level shuffle across lg
    float tm[2];
#pragma unroll
    for (int g = 0; g < 2; ++g) {
      float a01 = fmaxf(fmaxf(sf[g][0][0], sf[g][0][1]), fmaxf(sf[g][0][2], sf[g][0][3]));
      float a23 = fmaxf(fmaxf(sf[g][1][0], sf[g][1][1]), fmaxf(sf[g][1][2], sf[g][1][3]));
      float a45 = fmaxf(fmaxf(sf[g][2][0], sf[g][2][1]), fmaxf(sf[g][2][2], sf[g][2][3]));
      float a67 = fmaxf(fmaxf(sf[g][3][0], sf[g][3][1]), fmaxf(sf[g][3][2], sf[g][3][3]));
      float m = fmaxf(fmaxf(a01, a23), fmaxf(a45, a67));
      m = fmaxf(m, __shfl_xor(m, 16));
      m = fmaxf(m, __shfl_xor(m, 32));
      tm[g] = m;
    }
    // T13 defer-max: rescale only when a row max grew by > 8 (exp2-domain; P <= 256)
    if (__any((tm[0] > mrun[0] + 8.f) || (tm[1] > mrun[1] + 8.f))) {
      float nm0 = fmaxf(mrun[0], tm[0]), nm1 = fmaxf(mrun[1], tm[1]);
      float a0 = exp2f(mrun[0] - nm0), a1 = exp2f(mrun[1] - nm1);
      mrun[0] = nm0; mrun[1] = nm1;
      float aO0[4], aO1[4];
#pragma unroll
      for (int j = 0; j < 4; ++j) {
        aO0[j] = __shfl(a0, lg * 4 + j);   // broadcast to o-layout (qrow = lg*4+j)
        aO1[j] = __shfl(a1, lg * 4 + j);
      }
#pragma unroll
      for (int c = 0; c < 6; ++c)
#pragma unroll
        for (int j = 0; j < 4; ++j) {
          o[0][c][j] *= aO0[j];
          o[1][c][j] *= aO1[j];
        }
    }
    // P = exp2(S - m); stash b64 into [qrow][key] (wave-private, in-wave LDS dep)
#pragma unroll
    for (int g = 0; g < 2; ++g)
#pragma unroll
      for (int f = 0; f < 4; ++f) {
        ushort4 pk;
        pk.x = f2b(exp2f(sf[g][f][0] - mrun[g]));
        pk.y = f2b(exp2f(sf[g][f][1] - mrun[g]));
        pk.z = f2b(exp2f(sf[g][f][2] - mrun[g]));
        pk.w = f2b(exp2f(sf[g][f][3] - mrun[g]));
        *(ushort4*)(SPw + (g * 16 + lr) * SP + f * 16 + lg * 4) = pk;
      }

    // O[32 x 96] += P · V   (col=lr=d, row=lg*4+j=qrow)
#pragma unroll
    for (int t2 = 0; t2 < 2; ++t2) {
      bf16x8 pa0 = *(const bf16x8*)(SPw + lr * SP + t2 * 32 + lg * 8);
      bf16x8 pa1 = *(const bf16x8*)(SPw + (16 + lr) * SP + t2 * 32 + lg * 8);
#pragma unroll
      for (int c = 0; c < 6; ++c) {
        bf16x8 bv_ = *(const bf16x8*)(lV + (c * 16 + lr) * VP + t2 * 32 + lg * 8);
        o[0][c] = MFMA16(pa0, bv_, o[0][c]);
        o[1][c] = MFMA16(pa1, bv_, o[1][c]);
      }
    }
    __syncthreads();
#pragma unroll
    for (int s = 0; s < 5; ++s) *(bf16x8*)(ldst[s]) = pre[s];
    __syncthreads();
  }

  // epilogue: denominator = ones-column (d-col 80 -> lane lr==0 of each lg group)
#pragma unroll
  for (int g = 0; g < 2; ++g) {
#pragma unroll
    for (int j = 0; j < 4; ++j) {
      float den = __shfl(o[g][5][j], (l & 48));
      float inv = 1.0f / den;
      int qg = q0 + w * 32 + g * 16 + lg * 4 + j;
      float* ob = out + ((size_t)b_ * 2048 + qg) * 768 + h * 64;
#pragma unroll
      for (int c = 0; c < 4; ++c) ob[c * 16 + lr] = o[g][c][j] * inv;
      out2[((size_t)b_ * 2048 + qg) * 192 + h * 16 + lr] = o[g][4][j] * inv;
    }
  }
}

// ---------- launch ----------
extern "C" void kernel_launch(void* const* d_in, const int* in_sizes, int n_in,
                              void* d_out, int out_size, void* d_ws, size_t ws_size,
                              hipStream_t stream) {
  const float* hidden = (const float*)d_in[0];
  const float* lhidden = (const float*)d_in[1];
  const float* mask = (const float*)d_in[2];
  const float* Wq = (const float*)d_in[3];
  const float* bq = (const float*)d_in[4];
  const float* Wk = (const float*)d_in[5];
  const float* bk = (const float*)d_in[6];
  const float* Wv = (const float*)d_in[7];
  const float* bv = (const float*)d_in[8];
  const float* LWq = (const float*)d_in[9];
  const float* Lbq = (const float*)d_in[10];
  const float* LWk = (const float*)d_in[11];
  const float* Lbk = (const float*)d_in[12];
  const float* LWv = (const float*)d_in[13];
  const float* Lbv = (const float*)d_in[14];

  char* ws = (char*)d_ws;
  __hip_bfloat16* Xb  = (__hip_bfloat16*)(ws + 0);          // 12582912 B
  __hip_bfloat16* LXb = (__hip_bfloat16*)(ws + 12582912);   //  3145728 B
  __hip_bfloat16* Wt  = (__hip_bfloat16*)(ws + 15728640);   //  3538944 B
  __hip_bfloat16* LWt = (__hip_bfloat16*)(ws + 19267584);   //   294912 B
  __hip_bfloat16* qcb = (__hip_bfloat16*)(ws + 19562496);   // 15728640 B
  __hip_bfloat16* kcb = (__hip_bfloat16*)(ws + 35291136);   // 15728640 B
  __hip_bfloat16* vtb = (__hip_bfloat16*)(ws + 51019776);   // 15728640 B  (end 66748416)

  float* out = (float*)d_out;
  float* out2 = out + (size_t)4 * 2048 * 768;

  cvt_f32_bf16<<<2048, 256, 0, stream>>>(hidden, Xb, 6291456);
  cvt_f32_bf16<<<1024, 256, 0, stream>>>(lhidden, LXb, 1572864);
  transpose_cvt<<<dim3(24, 24, 3), 256, 0, stream>>>(Wq, Wk, Wv, Wt, 768, 768, 768);
  transpose_cvt<<<dim3(8, 6, 3), 256, 0, stream>>>(LWq, LWk, LWv, LWt, 192, 192, 256);

  // q pre-scaled into exp2 domain: 1/(8 ln2), layout-q: 1/(4 ln2)
  proj_gemm<768, 768, 768, 64, 0><<<dim3(64, 6, 3), 256, 0, stream>>>(
      Xb, Wt, bq, bk, bv, qcb, kcb, vtb, 0.125f * INVLN2);
  proj_gemm<192, 192, 256, 16, 64><<<dim3(64, 2, 3), 256, 0, stream>>>(
      LXb, LWt, Lbq, Lbk, Lbv, qcb, kcb, vtb, 0.25f * INVLN2);

  attn_kernel<<<dim3(16, 48), 256, 0, stream>>>(qcb, kcb, vtb, mask, out, out2);
}

// Round 5
// 291.599 us; speedup vs baseline: 1.4634x; 1.0963x over previous
//
#include <hip/hip_runtime.h>
#include <hip/hip_bf16.h>
#include <cstdint>
#include <math.h>

// ---------- types / helpers ----------
typedef __attribute__((ext_vector_type(8))) short bf16x8;   // 8 bf16 in 4 VGPRs
typedef __attribute__((ext_vector_type(4))) short bf16x4;   // 8B
typedef __attribute__((ext_vector_type(4))) float f32x4;
typedef __attribute__((ext_vector_type(16))) float f32x16;

#define MFMA16(a, b, c) __builtin_amdgcn_mfma_f32_16x16x32_bf16((a), (b), (c), 0, 0, 0)
#define MFMA32(a, b, c) __builtin_amdgcn_mfma_f32_32x32x16_bf16((a), (b), (c), 0, 0, 0)
// MFMA32 C/D: col=lane&31 (N), row=(reg&3)+8*(reg>>2)+4*(lane>>5) (M), reg 0..15
// A (M=32,K=16): lane holds row m=lane&31, k=(lane>>5)*8+j ; B (K=16,N=32): col n=lane&31, same k.

static __device__ __forceinline__ unsigned short f2b(float x) {
  __hip_bfloat16 h = __float2bfloat16(x);
  return __builtin_bit_cast(unsigned short, h);
}

static __device__ __forceinline__ void gload16(const void* g, void* l) {
  __builtin_amdgcn_global_load_lds((const __attribute__((address_space(1))) void*)g,
                                   (__attribute__((address_space(3))) void*)l, 16, 0, 0);
}

#define INVLN2 1.4426950408889634f

// ---------- f32 -> bf16 elementwise convert ----------
__global__ __launch_bounds__(256) void cvt_f32_bf16(const float* __restrict__ s,
                                                    __hip_bfloat16* __restrict__ d, int n) {
  int stride = gridDim.x * 256 * 4;
  for (int i = (blockIdx.x * 256 + threadIdx.x) * 4; i < n; i += stride) {
    float4 v = *(const float4*)(s + i);
    ushort4 o;
    o.x = f2b(v.x); o.y = f2b(v.y); o.z = f2b(v.z); o.w = f2b(v.w);
    *(ushort4*)&d[i] = o;
  }
}

// ---------- transpose-convert weights: dst[p][n][k] = (bf16) src_p[k][n], zero pad n in [N,Npad) ----------
__global__ __launch_bounds__(256) void transpose_cvt(const float* __restrict__ s0,
                                                     const float* __restrict__ s1,
                                                     const float* __restrict__ s2,
                                                     __hip_bfloat16* __restrict__ dst,
                                                     int K, int N, int Npad) {
  __shared__ float tile[32][33];
  int p = blockIdx.z;
  const float* src = (p == 0) ? s0 : (p == 1) ? s1 : s2;
  int n0 = blockIdx.x * 32, k0 = blockIdx.y * 32;
  int tx = threadIdx.x & 31, ty = threadIdx.x >> 5;  // 32 x 8
  for (int i = ty; i < 32; i += 8) {
    int k = k0 + i, n = n0 + tx;
    tile[i][tx] = (k < K && n < N) ? src[(size_t)k * N + n] : 0.f;
  }
  __syncthreads();
  for (int i = ty; i < 32; i += 8) {
    int n = n0 + i, k = k0 + tx;
    if (n < Npad && k < K)
      dst[(size_t)p * Npad * K + (size_t)n * K + k] = __float2bfloat16(tile[tx][i]);
  }
}

// ---------- projection GEMM: Y = X[M,K] @ Wt[N,K]^T + bias ----------
// computes C^T via swapped MFMA operands; p=0 -> qc (scaled), p=1 -> kc, p=2 -> vt (direct-transposed)
template <int K, int N, int NPAD, int HD, int COFF>
__global__ __launch_bounds__(256, 2) void proj_gemm(
    const __hip_bfloat16* __restrict__ X, const __hip_bfloat16* __restrict__ Wt,
    const float* __restrict__ bq, const float* __restrict__ bk, const float* __restrict__ bv,
    __hip_bfloat16* __restrict__ qc, __hip_bfloat16* __restrict__ kc,
    __hip_bfloat16* __restrict__ vt, float qscale) {
  __shared__ __hip_bfloat16 lA[128 * 32];
  __shared__ __hip_bfloat16 lB[128 * 32];
  const int tid = threadIdx.x, w = tid >> 6, l = tid & 63;
  const int lr = l & 15, lg = l >> 4;
  const int p = blockIdx.z;
  const int m0 = blockIdx.x * 128, n0 = blockIdx.y * 128;
  const __hip_bfloat16* Wp = Wt + (size_t)p * NPAD * K;
  const float* bias = (p == 0) ? bq : (p == 1) ? bk : bv;
  const float scale = (p == 0) ? qscale : 1.0f;

  f32x4 acc[4][4] = {};

  const int srow = (w * 2) * 16 + (l >> 2);
  const int scol = (l & 3) * 8;
  const __hip_bfloat16* gA = X + (size_t)(m0 + srow) * K + scol;
  const __hip_bfloat16* gB = Wp + (size_t)(n0 + srow) * K + scol;
  __hip_bfloat16* dA = lA + (w * 2) * 512;  // wave-uniform LDS base
  __hip_bfloat16* dB = lB + (w * 2) * 512;
  const int wr = w >> 1, wc = w & 1;

  for (int kk = 0; kk < K; kk += 32) {
    gload16(gA + kk, dA);
    gload16(gA + (size_t)16 * K + kk, dA + 512);
    gload16(gB + kk, dB);
    gload16(gB + (size_t)16 * K + kk, dB + 512);
    __syncthreads();
    bf16x8 af[4], bfr[4];
#pragma unroll
    for (int i = 0; i < 4; i++) af[i] = *(const bf16x8*)(lA + (wr * 64 + i * 16 + lr) * 32 + lg * 8);
#pragma unroll
    for (int j = 0; j < 4; j++) bfr[j] = *(const bf16x8*)(lB + (wc * 64 + j * 16 + lr) * 32 + lg * 8);
#pragma unroll
    for (int i = 0; i < 4; i++)
#pragma unroll
      for (int j = 0; j < 4; j++) acc[i][j] = MFMA16(bfr[j], af[i], acc[i][j]);  // C^T
    __syncthreads();
  }

  // epilogue: thread owns 4 consecutive n (regs) x 16 m (lr) per (i,j)
#pragma unroll
  for (int j = 0; j < 4; j++) {
    int nb = n0 + wc * 64 + j * 16 + lg * 4;
    if (NPAD > N && nb >= N) continue;
    float4 bv4 = *(const float4*)(bias + nb);
    int hh = nb / HD, d0 = nb % HD;
#pragma unroll
    for (int i = 0; i < 4; i++) {
      int m = m0 + wr * 64 + i * 16 + lr;
      int bb = m >> 11, s = m & 2047;
      if (p == 2) {
        // direct-transposed V: vt[bh][80][2048]
        size_t based = ((size_t)(bb * 12 + hh) * 80 + COFF + d0) * 2048 + s;
        vt[based]          = __float2bfloat16(acc[i][j][0] + bv4.x);
        vt[based + 2048]   = __float2bfloat16(acc[i][j][1] + bv4.y);
        vt[based + 4096]   = __float2bfloat16(acc[i][j][2] + bv4.z);
        vt[based + 6144]   = __float2bfloat16(acc[i][j][3] + bv4.w);
      } else {
        size_t base = ((size_t)(bb * 12 + hh) * 2048 + s) * 80 + COFF + d0;
        ushort4 st;
        st.x = f2b((acc[i][j][0] + bv4.x) * scale);
        st.y = f2b((acc[i][j][1] + bv4.y) * scale);
        st.z = f2b((acc[i][j][2] + bv4.z) * scale);
        st.w = f2b((acc[i][j][3] + bv4.w) * scale);
        *(ushort4*)((p == 0 ? qc : kc) + base) = st;
      }
    }
  }
}

// ---------- fused flash attention: 32x32 MFMA, register-resident P, permuted-linear LDS ----------
// qc/kc: [bh][2048][80] bf16 (q pre-scaled by 1/(8 ln2) resp 1/(4 ln2)); vt: [bh][80][2048] bf16
// lK layout: [c=dk/8][key 64][8]   (c-block stride 512 elems) -- read & gload_lds both linear
// lV layout: [g][d 96][8] granule stride 776 elems; granule g=(kb*2+ks)*2+hi holds, for row d,
//            elems j=0..7 = V[key 32kb+16ks+4hi+(j&3)+8*(j>>2)][d]  (sigma-order = S-reg order)
__global__ __launch_bounds__(256, 3) void attn_kernel(
    const __hip_bfloat16* __restrict__ qc, const __hip_bfloat16* __restrict__ kc,
    const __hip_bfloat16* __restrict__ vt, const float* __restrict__ mask,
    float* __restrict__ out, float* __restrict__ out2) {
  __shared__ __hip_bfloat16 lK[2][10 * 512];
  __shared__ __hip_bfloat16 lV[2][8 * 776];
  const int tid = threadIdx.x, w = tid >> 6, l = tid & 63;
  const int hi = l >> 5, ln = l & 31;
  const int bh = blockIdx.y, b_ = bh / 12, h = bh - b_ * 12;
  const int q0 = blockIdx.x * 128;

  const __hip_bfloat16* kbase = kc + ((size_t)bh * 2048 + l) * 80;  // + kv*80 + c*8
  const __hip_bfloat16* vbase = vt + (size_t)bh * 80 * 2048;
  const float* maskb = mask + b_ * 2048;

  // V staging slot geometry: vi = {tid, tid+256, tid+512(tid<128)}; d=vi>>3, a=vi&7
  const int vd0 = tid >> 3, va0 = tid & 7;
  const int vd1 = (tid + 256) >> 3, va1 = tid & 7;
  const int vd2 = (tid + 512) >> 3, va2 = tid & 7;

  // --- Q fragments (held whole block): qrow = q0 + w*32 + ln, 5 k-steps of 16 ---
  bf16x8 aq[5];
  {
    const __hip_bfloat16* qp = qc + ((size_t)bh * 2048 + q0 + w * 32 + ln) * 80 + hi * 8;
#pragma unroll
    for (int t = 0; t < 5; ++t) aq[t] = *(const bf16x8*)(qp + t * 16);
  }

  // --- prologue: ones/zero rows (d 80..95) of both V buffers; stage tile 0 into buf 0 ---
  {
    int buf = tid >> 7, g = (tid >> 4) & 7, row = 80 + (tid & 15);
    short v = (row == 80) ? (short)0x3F80 : (short)0;
    bf16x8 x = {v, v, v, v, v, v, v, v};
    *(bf16x8*)(&lV[buf][g * 776 + row * 8]) = x;
  }
  {
    const __hip_bfloat16* kg = kbase;  // kv0 = 0
    gload16(kg + w * 8, &lK[0][w * 512]);
    gload16(kg + (4 + w) * 8, &lK[0][(4 + w) * 512]);
    if (w < 2) gload16(kg + (8 + w) * 8, &lK[0][(8 + w) * 512]);
    bf16x8 v0 = *(const bf16x8*)(vbase + (size_t)vd0 * 2048 + va0 * 8);
    bf16x8 v1 = *(const bf16x8*)(vbase + (size_t)vd1 * 2048 + va1 * 8);
    *(bf16x4*)(&lV[0][(va0 & 6) * 776 + vd0 * 8 + (va0 & 1) * 4]) = bf16x4{v0[0], v0[1], v0[2], v0[3]};
    *(bf16x4*)(&lV[0][((va0 & 6) | 1) * 776 + vd0 * 8 + (va0 & 1) * 4]) = bf16x4{v0[4], v0[5], v0[6], v0[7]};
    *(bf16x4*)(&lV[0][(va1 & 6) * 776 + vd1 * 8 + (va1 & 1) * 4]) = bf16x4{v1[0], v1[1], v1[2], v1[3]};
    *(bf16x4*)(&lV[0][((va1 & 6) | 1) * 776 + vd1 * 8 + (va1 & 1) * 4]) = bf16x4{v1[4], v1[5], v1[6], v1[7]};
    if (tid < 128) {
      bf16x8 v2 = *(const bf16x8*)(vbase + (size_t)vd2 * 2048 + va2 * 8);
      *(bf16x4*)(&lV[0][(va2 & 6) * 776 + vd2 * 8 + (va2 & 1) * 4]) = bf16x4{v2[0], v2[1], v2[2], v2[3]};
      *(bf16x4*)(&lV[0][((va2 & 6) | 1) * 776 + vd2 * 8 + (va2 & 1) * 4]) = bf16x4{v2[4], v2[5], v2[6], v2[7]};
    }
  }
  __syncthreads();

  float mrun = -INFINITY;          // running max for qrow = ln (dup across hi)
  f32x16 o0 = {}, o1 = {}, o2 = {};

  for (int kt = 0; kt < 32; ++kt) {
    const int cur = kt & 1, nxt = cur ^ 1;
    const int kvn = (kt + 1 < 32) ? (kt + 1) * 64 : kt * 64;
    const int kv0 = kt * 64;

    // ---- stage next K tile via global_load_lds (direct to LDS, buf nxt) ----
    {
      const __hip_bfloat16* kg = kbase + (size_t)kvn * 80;
      gload16(kg + w * 8, &lK[nxt][w * 512]);
      gload16(kg + (4 + w) * 8, &lK[nxt][(4 + w) * 512]);
      if (w < 2) gload16(kg + (8 + w) * 8, &lK[nxt][(8 + w) * 512]);
    }
    // ---- T14: issue next V tile global loads early ----
    bf16x8 v0 = *(const bf16x8*)(vbase + (size_t)vd0 * 2048 + kvn + va0 * 8);
    bf16x8 v1 = *(const bf16x8*)(vbase + (size_t)vd1 * 2048 + kvn + va1 * 8);
    bf16x8 v2;
    if (tid < 128) v2 = *(const bf16x8*)(vbase + (size_t)vd2 * 2048 + kvn + va2 * 8);

    // ---- QK: S^T[key][qrow], lane=qrow ln, regs = 16 keys per 32-key block ----
    const __hip_bfloat16* lKc = &lK[cur][0];
    f32x16 sf0 = {}, sf1 = {};
#pragma unroll
    for (int t = 0; t < 5; ++t) {
      bf16x8 ak0 = *(const bf16x8*)(lKc + (t * 2 + hi) * 512 + ln * 8);
      bf16x8 ak1 = *(const bf16x8*)(lKc + (t * 2 + hi) * 512 + (32 + ln) * 8);
      sf0 = MFMA32(ak0, aq[t], sf0);
      sf1 = MFMA32(ak1, aq[t], sf1);
    }

    // ---- mask add (keys for reg r: kb*32 + 4*hi + (r&3) + 8*(r>>2)) ----
    float s_[2][16];
#pragma unroll
    for (int q = 0; q < 4; ++q) {
      float4 m0 = *(const float4*)(maskb + kv0 + 4 * hi + q * 8);
      float4 m1 = *(const float4*)(maskb + kv0 + 32 + 4 * hi + q * 8);
#pragma unroll
      for (int c = 0; c < 4; ++c) {
        s_[0][q * 4 + c] = sf0[q * 4 + c] + ((const float*)&m0)[c] * INVLN2;
        s_[1][q * 4 + c] = sf1[q * 4 + c] + ((const float*)&m1)[c] * INVLN2;
      }
    }

    // ---- online max (T13 defer) ----
    float tm = s_[0][0];
#pragma unroll
    for (int r = 1; r < 16; ++r) tm = fmaxf(tm, s_[0][r]);
#pragma unroll
    for (int r = 0; r < 16; ++r) tm = fmaxf(tm, s_[1][r]);
    tm = fmaxf(tm, __shfl_xor(tm, 32));
    if (__any(tm > mrun + 8.f)) {
      float nm = fmaxf(mrun, tm);
      float alpha = exp2f(mrun - nm);
      mrun = nm;
#pragma unroll
      for (int r = 0; r < 16; ++r) {
        float a = __shfl(alpha, (r & 3) + 8 * (r >> 2) + 4 * hi);
        o0[r] *= a; o1[r] *= a; o2[r] *= a;
      }
    }

    // ---- P = exp2(S - m), pack to A-frags in sigma order (pure lane-local) ----
    bf16x8 pa[2][2];
#pragma unroll
    for (int kb = 0; kb < 2; ++kb)
#pragma unroll
      for (int ks = 0; ks < 2; ++ks) {
        bf16x8 pk;
#pragma unroll
        for (int j = 0; j < 8; ++j)
          pk[j] = (short)f2b(exp2f(s_[kb][ks * 8 + j] - mrun));
        pa[kb][ks] = pk;
      }

    // ---- PV: O[qrow][d 0..95] ----
    const __hip_bfloat16* lVc = &lV[cur][0];
#pragma unroll
    for (int kb = 0; kb < 2; ++kb)
#pragma unroll
      for (int ks = 0; ks < 2; ++ks) {
        const int g = (kb * 2 + ks) * 2 + hi;
        bf16x8 bv0 = *(const bf16x8*)(lVc + g * 776 + ln * 8);
        bf16x8 bv1 = *(const bf16x8*)(lVc + g * 776 + (32 + ln) * 8);
        bf16x8 bv2 = *(const bf16x8*)(lVc + g * 776 + (64 + ln) * 8);
        o0 = MFMA32(pa[kb][ks], bv0, o0);
        o1 = MFMA32(pa[kb][ks], bv1, o1);
        o2 = MFMA32(pa[kb][ks], bv2, o2);
      }

    // ---- write staged V regs into buf nxt (sigma-split b64 pairs) ----
    *(bf16x4*)(&lV[nxt][(va0 & 6) * 776 + vd0 * 8 + (va0 & 1) * 4]) = bf16x4{v0[0], v0[1], v0[2], v0[3]};
    *(bf16x4*)(&lV[nxt][((va0 & 6) | 1) * 776 + vd0 * 8 + (va0 & 1) * 4]) = bf16x4{v0[4], v0[5], v0[6], v0[7]};
    *(bf16x4*)(&lV[nxt][(va1 & 6) * 776 + vd1 * 8 + (va1 & 1) * 4]) = bf16x4{v1[0], v1[1], v1[2], v1[3]};
    *(bf16x4*)(&lV[nxt][((va1 & 6) | 1) * 776 + vd1 * 8 + (va1 & 1) * 4]) = bf16x4{v1[4], v1[5], v1[6], v1[7]};
    if (tid < 128) {
      *(bf16x4*)(&lV[nxt][(va2 & 6) * 776 + vd2 * 8 + (va2 & 1) * 4]) = bf16x4{v2[0], v2[1], v2[2], v2[3]};
      *(bf16x4*)(&lV[nxt][((va2 & 6) | 1) * 776 + vd2 * 8 + (va2 & 1) * 4]) = bf16x4{v2[4], v2[5], v2[6], v2[7]};
    }
    __syncthreads();
  }

  // ---- epilogue: denominator = ones-row (d=80 -> col 16 of block 2) ----
#pragma unroll
  for (int r = 0; r < 16; ++r) {
    float den = __shfl(o2[r], 16 | (l & 32));
    float inv = 1.0f / den;
    int qg = q0 + w * 32 + (r & 3) + 8 * (r >> 2) + 4 * hi;
    size_t rowb = (size_t)b_ * 2048 + qg;
    out[rowb * 768 + h * 64 + ln] = o0[r] * inv;
    out[rowb * 768 + h * 64 + 32 + ln] = o1[r] * inv;
    if (ln < 16) out2[rowb * 192 + h * 16 + ln] = o2[r] * inv;
  }
}

// ---------- launch ----------
extern "C" void kernel_launch(void* const* d_in, const int* in_sizes, int n_in,
                              void* d_out, int out_size, void* d_ws, size_t ws_size,
                              hipStream_t stream) {
  const float* hidden = (const float*)d_in[0];
  const float* lhidden = (const float*)d_in[1];
  const float* mask = (const float*)d_in[2];
  const float* Wq = (const float*)d_in[3];
  const float* bq = (const float*)d_in[4];
  const float* Wk = (const float*)d_in[5];
  const float* bk = (const float*)d_in[6];
  const float* Wv = (const float*)d_in[7];
  const float* bv = (const float*)d_in[8];
  const float* LWq = (const float*)d_in[9];
  const float* Lbq = (const float*)d_in[10];
  const float* LWk = (const float*)d_in[11];
  const float* Lbk = (const float*)d_in[12];
  const float* LWv = (const float*)d_in[13];
  const float* Lbv = (const float*)d_in[14];

  char* ws = (char*)d_ws;
  __hip_bfloat16* Xb  = (__hip_bfloat16*)(ws + 0);          // 12582912 B
  __hip_bfloat16* LXb = (__hip_bfloat16*)(ws + 12582912);   //  3145728 B
  __hip_bfloat16* Wt  = (__hip_bfloat16*)(ws + 15728640);   //  3538944 B
  __hip_bfloat16* LWt = (__hip_bfloat16*)(ws + 19267584);   //   294912 B
  __hip_bfloat16* qcb = (__hip_bfloat16*)(ws + 19562496);   // 15728640 B
  __hip_bfloat16* kcb = (__hip_bfloat16*)(ws + 35291136);   // 15728640 B
  __hip_bfloat16* vtb = (__hip_bfloat16*)(ws + 51019776);   // 15728640 B  (end 66748416)

  float* out = (float*)d_out;
  float* out2 = out + (size_t)4 * 2048 * 768;

  cvt_f32_bf16<<<2048, 256, 0, stream>>>(hidden, Xb, 6291456);
  cvt_f32_bf16<<<1024, 256, 0, stream>>>(lhidden, LXb, 1572864);
  transpose_cvt<<<dim3(24, 24, 3), 256, 0, stream>>>(Wq, Wk, Wv, Wt, 768, 768, 768);
  transpose_cvt<<<dim3(8, 6, 3), 256, 0, stream>>>(LWq, LWk, LWv, LWt, 192, 192, 256);

  // q pre-scaled into exp2 domain: 1/(8 ln2), layout-q: 1/(4 ln2)
  proj_gemm<768, 768, 768, 64, 0><<<dim3(64, 6, 3), 256, 0, stream>>>(
      Xb, Wt, bq, bk, bv, qcb, kcb, vtb, 0.125f * INVLN2);
  proj_gemm<192, 192, 256, 16, 64><<<dim3(64, 2, 3), 256, 0, stream>>>(
      LXb, LWt, Lbq, Lbk, Lbv, qcb, kcb, vtb, 0.25f * INVLN2);

  attn_kernel<<<dim3(16, 48), 256, 0, stream>>>(qcb, kcb, vtb, mask, out, out2);
}

// Round 10
// 287.544 us; speedup vs baseline: 1.4840x; 1.0141x over previous
//
#include <hip/hip_runtime.h>
#include <hip/hip_bf16.h>
#include <cstdint>
#include <math.h>

// ---------- types / helpers ----------
typedef __attribute__((ext_vector_type(8))) short bf16x8;   // 8 bf16 in 4 VGPRs
typedef __attribute__((ext_vector_type(4))) short bf16x4;   // 8B
typedef __attribute__((ext_vector_type(4))) float f32x4;
typedef __attribute__((ext_vector_type(16))) float f32x16;

#define MFMA16(a, b, c) __builtin_amdgcn_mfma_f32_16x16x32_bf16((a), (b), (c), 0, 0, 0)
#define MFMA32(a, b, c) __builtin_amdgcn_mfma_f32_32x32x16_bf16((a), (b), (c), 0, 0, 0)
// MFMA32 C/D: col=lane&31 (N), row=(reg&3)+8*(reg>>2)+4*(lane>>5) (M), reg 0..15
// A (M=32,K=16): lane holds row m=lane&31, k=(lane>>5)*8+j ; B (K=16,N=32): col n=lane&31, same k.

static __device__ __forceinline__ unsigned short f2b(float x) {
  __hip_bfloat16 h = __float2bfloat16(x);
  return __builtin_bit_cast(unsigned short, h);
}

static __device__ __forceinline__ void gload16(const void* g, void* l) {
  __builtin_amdgcn_global_load_lds((const __attribute__((address_space(1))) void*)g,
                                   (__attribute__((address_space(3))) void*)l, 16, 0, 0);
}

#define INVLN2 1.4426950408889634f

// ---------- f32 -> bf16 elementwise convert ----------
__global__ __launch_bounds__(256) void cvt_f32_bf16(const float* __restrict__ s,
                                                    __hip_bfloat16* __restrict__ d, int n) {
  int stride = gridDim.x * 256 * 4;
  for (int i = (blockIdx.x * 256 + threadIdx.x) * 4; i < n; i += stride) {
    float4 v = *(const float4*)(s + i);
    ushort4 o;
    o.x = f2b(v.x); o.y = f2b(v.y); o.z = f2b(v.z); o.w = f2b(v.w);
    *(ushort4*)&d[i] = o;
  }
}

// ---------- mask prescale: maskx = mask * INVLN2 ----------
__global__ __launch_bounds__(256) void maskx_scale(const float* __restrict__ s,
                                                   float* __restrict__ d, int n) {
  int i = (blockIdx.x * 256 + threadIdx.x) * 4;
  if (i < n) {
    float4 v = *(const float4*)(s + i);
    v.x *= INVLN2; v.y *= INVLN2; v.z *= INVLN2; v.w *= INVLN2;
    *(float4*)(d + i) = v;
  }
}

// ---------- transpose-convert weights: dst[p][n][k] = (bf16) src_p[k][n], zero pad n in [N,Npad) ----------
__global__ __launch_bounds__(256) void transpose_cvt(const float* __restrict__ s0,
                                                     const float* __restrict__ s1,
                                                     const float* __restrict__ s2,
                                                     __hip_bfloat16* __restrict__ dst,
                                                     int K, int N, int Npad) {
  __shared__ float tile[32][33];
  int p = blockIdx.z;
  const float* src = (p == 0) ? s0 : (p == 1) ? s1 : s2;
  int n0 = blockIdx.x * 32, k0 = blockIdx.y * 32;
  int tx = threadIdx.x & 31, ty = threadIdx.x >> 5;  // 32 x 8
  for (int i = ty; i < 32; i += 8) {
    int k = k0 + i, n = n0 + tx;
    tile[i][tx] = (k < K && n < N) ? src[(size_t)k * N + n] : 0.f;
  }
  __syncthreads();
  for (int i = ty; i < 32; i += 8) {
    int n = n0 + i, k = k0 + tx;
    if (n < Npad && k < K)
      dst[(size_t)p * Npad * K + (size_t)n * K + k] = __float2bfloat16(tile[tx][i]);
  }
}

// ---------- projection GEMM: Y = X[M,K] @ Wt[N,K]^T + bias (double-buffered LDS, 1 barrier/k-step) ----------
// computes C^T via swapped MFMA operands; p=0 -> qc (scaled), p=1 -> kc, p=2 -> vt (direct-transposed)
template <int K, int N, int NPAD, int HD, int COFF>
__global__ __launch_bounds__(256, 2) void proj_gemm(
    const __hip_bfloat16* __restrict__ X, const __hip_bfloat16* __restrict__ Wt,
    const float* __restrict__ bq, const float* __restrict__ bk, const float* __restrict__ bv,
    __hip_bfloat16* __restrict__ qc, __hip_bfloat16* __restrict__ kc,
    __hip_bfloat16* __restrict__ vt, float qscale) {
  __shared__ __hip_bfloat16 lA[2][128 * 32];
  __shared__ __hip_bfloat16 lB[2][128 * 32];
  const int tid = threadIdx.x, w = tid >> 6, l = tid & 63;
  const int lr = l & 15, lg = l >> 4;
  const int p = blockIdx.z;
  const int m0 = blockIdx.x * 128, n0 = blockIdx.y * 128;
  const __hip_bfloat16* Wp = Wt + (size_t)p * NPAD * K;
  const float* bias = (p == 0) ? bq : (p == 1) ? bk : bv;
  const float scale = (p == 0) ? qscale : 1.0f;

  f32x4 acc[4][4] = {};

  const int srow = (w * 2) * 16 + (l >> 2);
  const int scol = (l & 3) * 8;
  const __hip_bfloat16* gA = X + (size_t)(m0 + srow) * K + scol;
  const __hip_bfloat16* gB = Wp + (size_t)(n0 + srow) * K + scol;
  const int wo = (w * 2) * 512;  // wave-uniform LDS base offset
  const int wr = w >> 1, wc = w & 1;
  constexpr int NK = K / 32;

  // prologue: stage k-step 0 into buf 0
  gload16(gA, &lA[0][wo]);
  gload16(gA + (size_t)16 * K, &lA[0][wo + 512]);
  gload16(gB, &lB[0][wo]);
  gload16(gB + (size_t)16 * K, &lB[0][wo + 512]);

  for (int t = 0; t < NK; ++t) {
    const int cur = t & 1;
    __syncthreads();  // drains cur's loads; all waves done reading buf cur^1 (at t-1)
    if (t + 1 < NK) {
      const int nx = cur ^ 1, kk = (t + 1) * 32;
      gload16(gA + kk, &lA[nx][wo]);
      gload16(gA + (size_t)16 * K + kk, &lA[nx][wo + 512]);
      gload16(gB + kk, &lB[nx][wo]);
      gload16(gB + (size_t)16 * K + kk, &lB[nx][wo + 512]);
    }
    bf16x8 af[4], bfr[4];
#pragma unroll
    for (int i = 0; i < 4; i++) af[i] = *(const bf16x8*)(&lA[cur][(wr * 64 + i * 16 + lr) * 32 + lg * 8]);
#pragma unroll
    for (int j = 0; j < 4; j++) bfr[j] = *(const bf16x8*)(&lB[cur][(wc * 64 + j * 16 + lr) * 32 + lg * 8]);
#pragma unroll
    for (int i = 0; i < 4; i++)
#pragma unroll
      for (int j = 0; j < 4; j++) acc[i][j] = MFMA16(bfr[j], af[i], acc[i][j]);  // C^T
  }

  // epilogue: thread owns 4 consecutive n (regs) x 16 m (lr) per (i,j)
#pragma unroll
  for (int j = 0; j < 4; j++) {
    int nb = n0 + wc * 64 + j * 16 + lg * 4;
    if (NPAD > N && nb >= N) continue;
    float4 bv4 = *(const float4*)(bias + nb);
    int hh = nb / HD, d0 = nb % HD;
#pragma unroll
    for (int i = 0; i < 4; i++) {
      int m = m0 + wr * 64 + i * 16 + lr;
      int bb = m >> 11, s = m & 2047;
      if (p == 2) {
        // direct-transposed V: vt[bh][80][2048]
        size_t based = ((size_t)(bb * 12 + hh) * 80 + COFF + d0) * 2048 + s;
        vt[based]          = __float2bfloat16(acc[i][j][0] + bv4.x);
        vt[based + 2048]   = __float2bfloat16(acc[i][j][1] + bv4.y);
        vt[based + 4096]   = __float2bfloat16(acc[i][j][2] + bv4.z);
        vt[based + 6144]   = __float2bfloat16(acc[i][j][3] + bv4.w);
      } else {
        size_t base = ((size_t)(bb * 12 + hh) * 2048 + s) * 80 + COFF + d0;
        ushort4 st;
        st.x = f2b((acc[i][j][0] + bv4.x) * scale);
        st.y = f2b((acc[i][j][1] + bv4.y) * scale);
        st.z = f2b((acc[i][j][2] + bv4.z) * scale);
        st.w = f2b((acc[i][j][3] + bv4.w) * scale);
        *(ushort4*)((p == 0 ? qc : kc) + base) = st;
      }
    }
  }
}

// ---------- fused flash attention: 32x32 MFMA, register-resident P, permuted-linear LDS ----------
// qc/kc: [bh][2048][80] bf16 (q pre-scaled by 1/(8 ln2) resp 1/(4 ln2)); vt: [bh][80][2048] bf16
// mxb: mask * INVLN2 (f32, per [b][key]) -- folded into QK MFMA via C-init
// lK layout: [c=dk/8][key 64][8]   (c-block stride 512 elems) -- read & gload_lds both linear
// lV layout: [g][d 96][8] granule stride 776 elems; granule g=(kb*2+ks)*2+hi holds, for row d,
//            elems j=0..7 = V[key 32kb+16ks+4hi+(j&3)+8*(j>>2)][d]  (sigma-order = S-reg order)
__global__ __launch_bounds__(256, 3) void attn_kernel(
    const __hip_bfloat16* __restrict__ qc, const __hip_bfloat16* __restrict__ kc,
    const __hip_bfloat16* __restrict__ vt, const float* __restrict__ mxb,
    float* __restrict__ out, float* __restrict__ out2) {
  __shared__ __hip_bfloat16 lK[2][10 * 512];
  __shared__ __hip_bfloat16 lV[2][8 * 776];
  const int tid = threadIdx.x, w = tid >> 6, l = tid & 63;
  const int hi = l >> 5, ln = l & 31;
  const int bh = blockIdx.y, b_ = bh / 12, h = bh - b_ * 12;
  const int q0 = blockIdx.x * 128;

  const __hip_bfloat16* kbase = kc + ((size_t)bh * 2048 + l) * 80;  // + kv*80 + c*8
  const __hip_bfloat16* vbase = vt + (size_t)bh * 80 * 2048;
  const float* maskb = mxb + b_ * 2048;

  // V staging slot geometry: vi = {tid, tid+256, tid+512(tid<128)}; d=vi>>3, a=vi&7
  const int vd0 = tid >> 3, va0 = tid & 7;
  const int vd1 = (tid + 256) >> 3, va1 = tid & 7;
  const int vd2 = (tid + 512) >> 3, va2 = tid & 7;

  // --- Q fragments (held whole block): qrow = q0 + w*32 + ln, 5 k-steps of 16 ---
  bf16x8 aq[5];
  {
    const __hip_bfloat16* qp = qc + ((size_t)bh * 2048 + q0 + w * 32 + ln) * 80 + hi * 8;
#pragma unroll
    for (int t = 0; t < 5; ++t) aq[t] = *(const bf16x8*)(qp + t * 16);
  }

  // --- prologue: ones/zero rows (d 80..95) of both V buffers; stage tile 0 into buf 0 ---
  {
    int buf = tid >> 7, g = (tid >> 4) & 7, row = 80 + (tid & 15);
    short v = (row == 80) ? (short)0x3F80 : (short)0;
    bf16x8 x = {v, v, v, v, v, v, v, v};
    *(bf16x8*)(&lV[buf][g * 776 + row * 8]) = x;
  }
  {
    const __hip_bfloat16* kg = kbase;  // kv0 = 0
    gload16(kg + w * 8, &lK[0][w * 512]);
    gload16(kg + (4 + w) * 8, &lK[0][(4 + w) * 512]);
    if (w < 2) gload16(kg + (8 + w) * 8, &lK[0][(8 + w) * 512]);
    bf16x8 v0 = *(const bf16x8*)(vbase + (size_t)vd0 * 2048 + va0 * 8);
    bf16x8 v1 = *(const bf16x8*)(vbase + (size_t)vd1 * 2048 + va1 * 8);
    *(bf16x4*)(&lV[0][(va0 & 6) * 776 + vd0 * 8 + (va0 & 1) * 4]) = bf16x4{v0[0], v0[1], v0[2], v0[3]};
    *(bf16x4*)(&lV[0][((va0 & 6) | 1) * 776 + vd0 * 8 + (va0 & 1) * 4]) = bf16x4{v0[4], v0[5], v0[6], v0[7]};
    *(bf16x4*)(&lV[0][(va1 & 6) * 776 + vd1 * 8 + (va1 & 1) * 4]) = bf16x4{v1[0], v1[1], v1[2], v1[3]};
    *(bf16x4*)(&lV[0][((va1 & 6) | 1) * 776 + vd1 * 8 + (va1 & 1) * 4]) = bf16x4{v1[4], v1[5], v1[6], v1[7]};
    if (tid < 128) {
      bf16x8 v2 = *(const bf16x8*)(vbase + (size_t)vd2 * 2048 + va2 * 8);
      *(bf16x4*)(&lV[0][(va2 & 6) * 776 + vd2 * 8 + (va2 & 1) * 4]) = bf16x4{v2[0], v2[1], v2[2], v2[3]};
      *(bf16x4*)(&lV[0][((va2 & 6) | 1) * 776 + vd2 * 8 + (va2 & 1) * 4]) = bf16x4{v2[4], v2[5], v2[6], v2[7]};
    }
  }
  __syncthreads();

  float mrun = -INFINITY;          // running max for qrow = ln (dup across hi)
  f32x16 o0 = {}, o1 = {}, o2 = {};

  for (int kt = 0; kt < 32; ++kt) {
    const int cur = kt & 1, nxt = cur ^ 1;
    const int kvn = (kt + 1 < 32) ? (kt + 1) * 64 : kt * 64;
    const int kv0 = kt * 64;

    // ---- stage next K tile via global_load_lds (direct to LDS, buf nxt) ----
    {
      const __hip_bfloat16* kg = kbase + (size_t)kvn * 80;
      gload16(kg + w * 8, &lK[nxt][w * 512]);
      gload16(kg + (4 + w) * 8, &lK[nxt][(4 + w) * 512]);
      if (w < 2) gload16(kg + (8 + w) * 8, &lK[nxt][(8 + w) * 512]);
    }
    // ---- T14: issue next V tile global loads early ----
    bf16x8 v0 = *(const bf16x8*)(vbase + (size_t)vd0 * 2048 + kvn + va0 * 8);
    bf16x8 v1 = *(const bf16x8*)(vbase + (size_t)vd1 * 2048 + kvn + va1 * 8);
    bf16x8 v2;
    if (tid < 128) v2 = *(const bf16x8*)(vbase + (size_t)vd2 * 2048 + kvn + va2 * 8);

    // ---- QK: S^T[key][qrow], lane=qrow ln, regs = 16 keys per 32-key block ----
    // C initialized from prescaled mask (key bias) -- rides the MFMA accumulate for free
    f32x16 sf0, sf1;
#pragma unroll
    for (int q = 0; q < 4; ++q) {
      float4 m0 = *(const float4*)(maskb + kv0 + 4 * hi + q * 8);
      float4 m1 = *(const float4*)(maskb + kv0 + 32 + 4 * hi + q * 8);
      sf0[q * 4 + 0] = m0.x; sf0[q * 4 + 1] = m0.y; sf0[q * 4 + 2] = m0.z; sf0[q * 4 + 3] = m0.w;
      sf1[q * 4 + 0] = m1.x; sf1[q * 4 + 1] = m1.y; sf1[q * 4 + 2] = m1.z; sf1[q * 4 + 3] = m1.w;
    }
    const __hip_bfloat16* lKc = &lK[cur][0];
#pragma unroll
    for (int t = 0; t < 5; ++t) {
      bf16x8 ak0 = *(const bf16x8*)(lKc + (t * 2 + hi) * 512 + ln * 8);
      bf16x8 ak1 = *(const bf16x8*)(lKc + (t * 2 + hi) * 512 + (32 + ln) * 8);
      sf0 = MFMA32(ak0, aq[t], sf0);
      sf1 = MFMA32(ak1, aq[t], sf1);
    }

    // ---- online max (v_max3 chain) + T13 defer ----
    float tm = fmaxf(sf0[0], sf0[1]);
#pragma unroll
    for (int r = 2; r < 16; r += 2) tm = fmaxf(fmaxf(tm, sf0[r]), sf0[r + 1]);
#pragma unroll
    for (int r = 0; r < 16; r += 2) tm = fmaxf(fmaxf(tm, sf1[r]), sf1[r + 1]);
    tm = fmaxf(tm, __shfl_xor(tm, 32));
    if (__any(tm > mrun + 8.f)) {
      float nm = fmaxf(mrun, tm);
      float alpha = exp2f(mrun - nm);
      mrun = nm;
#pragma unroll
      for (int r = 0; r < 16; ++r) {
        float a = __shfl(alpha, (r & 3) + 8 * (r >> 2) + 4 * hi);
        o0[r] *= a; o1[r] *= a; o2[r] *= a;
      }
    }

    // ---- P = exp2(S - m), pack to A-frags in sigma order (pure lane-local) ----
    bf16x8 pa[2][2];
#pragma unroll
    for (int ks = 0; ks < 2; ++ks) {
      bf16x8 pk0, pk1;
#pragma unroll
      for (int j = 0; j < 8; ++j) {
        pk0[j] = (short)f2b(exp2f(sf0[ks * 8 + j] - mrun));
        pk1[j] = (short)f2b(exp2f(sf1[ks * 8 + j] - mrun));
      }
      pa[0][ks] = pk0;
      pa[1][ks] = pk1;
    }

    // ---- PV: O[qrow][d 0..95] ----
    const __hip_bfloat16* lVc = &lV[cur][0];
#pragma unroll
    for (int kb = 0; kb < 2; ++kb)
#pragma unroll
      for (int ks = 0; ks < 2; ++ks) {
        const int g = (kb * 2 + ks) * 2 + hi;
        bf16x8 bv0 = *(const bf16x8*)(lVc + g * 776 + ln * 8);
        bf16x8 bv1 = *(const bf16x8*)(lVc + g * 776 + (32 + ln) * 8);
        bf16x8 bv2 = *(const bf16x8*)(lVc + g * 776 + (64 + ln) * 8);
        o0 = MFMA32(pa[kb][ks], bv0, o0);
        o1 = MFMA32(pa[kb][ks], bv1, o1);
        o2 = MFMA32(pa[kb][ks], bv2, o2);
      }

    // ---- write staged V regs into buf nxt (sigma-split b64 pairs) ----
    *(bf16x4*)(&lV[nxt][(va0 & 6) * 776 + vd0 * 8 + (va0 & 1) * 4]) = bf16x4{v0[0], v0[1], v0[2], v0[3]};
    *(bf16x4*)(&lV[nxt][((va0 & 6) | 1) * 776 + vd0 * 8 + (va0 & 1) * 4]) = bf16x4{v0[4], v0[5], v0[6], v0[7]};
    *(bf16x4*)(&lV[nxt][(va1 & 6) * 776 + vd1 * 8 + (va1 & 1) * 4]) = bf16x4{v1[0], v1[1], v1[2], v1[3]};
    *(bf16x4*)(&lV[nxt][((va1 & 6) | 1) * 776 + vd1 * 8 + (va1 & 1) * 4]) = bf16x4{v1[4], v1[5], v1[6], v1[7]};
    if (tid < 128) {
      *(bf16x4*)(&lV[nxt][(va2 & 6) * 776 + vd2 * 8 + (va2 & 1) * 4]) = bf16x4{v2[0], v2[1], v2[2], v2[3]};
      *(bf16x4*)(&lV[nxt][((va2 & 6) | 1) * 776 + vd2 * 8 + (va2 & 1) * 4]) = bf16x4{v2[4], v2[5], v2[6], v2[7]};
    }
    __syncthreads();
  }

  // ---- epilogue: denominator = ones-row (d=80 -> col 16 of block 2) ----
#pragma unroll
  for (int r = 0; r < 16; ++r) {
    float den = __shfl(o2[r], 16 | (l & 32));
    float inv = 1.0f / den;
    int qg = q0 + w * 32 + (r & 3) + 8 * (r >> 2) + 4 * hi;
    size_t rowb = (size_t)b_ * 2048 + qg;
    out[rowb * 768 + h * 64 + ln] = o0[r] * inv;
    out[rowb * 768 + h * 64 + 32 + ln] = o1[r] * inv;
    if (ln < 16) out2[rowb * 192 + h * 16 + ln] = o2[r] * inv;
  }
}

// ---------- launch ----------
extern "C" void kernel_launch(void* const* d_in, const int* in_sizes, int n_in,
                              void* d_out, int out_size, void* d_ws, size_t ws_size,
                              hipStream_t stream) {
  const float* hidden = (const float*)d_in[0];
  const float* lhidden = (const float*)d_in[1];
  const float* mask = (const float*)d_in[2];
  const float* Wq = (const float*)d_in[3];
  const float* bq = (const float*)d_in[4];
  const float* Wk = (const float*)d_in[5];
  const float* bk = (const float*)d_in[6];
  const float* Wv = (const float*)d_in[7];
  const float* bv = (const float*)d_in[8];
  const float* LWq = (const float*)d_in[9];
  const float* Lbq = (const float*)d_in[10];
  const float* LWk = (const float*)d_in[11];
  const float* Lbk = (const float*)d_in[12];
  const float* LWv = (const float*)d_in[13];
  const float* Lbv = (const float*)d_in[14];

  char* ws = (char*)d_ws;
  __hip_bfloat16* Xb  = (__hip_bfloat16*)(ws + 0);          // 12582912 B
  __hip_bfloat16* LXb = (__hip_bfloat16*)(ws + 12582912);   //  3145728 B
  __hip_bfloat16* Wt  = (__hip_bfloat16*)(ws + 15728640);   //  3538944 B
  __hip_bfloat16* LWt = (__hip_bfloat16*)(ws + 19267584);   //   294912 B
  __hip_bfloat16* qcb = (__hip_bfloat16*)(ws + 19562496);   // 15728640 B
  __hip_bfloat16* kcb = (__hip_bfloat16*)(ws + 35291136);   // 15728640 B
  __hip_bfloat16* vtb = (__hip_bfloat16*)(ws + 51019776);   // 15728640 B
  float*          mxb = (float*)(ws + 66748416);            //    32768 B  (end 66781184)

  float* out = (float*)d_out;
  float* out2 = out + (size_t)4 * 2048 * 768;

  cvt_f32_bf16<<<2048, 256, 0, stream>>>(hidden, Xb, 6291456);
  cvt_f32_bf16<<<1024, 256, 0, stream>>>(lhidden, LXb, 1572864);
  maskx_scale<<<8, 256, 0, stream>>>(mask, mxb, 8192);
  transpose_cvt<<<dim3(24, 24, 3), 256, 0, stream>>>(Wq, Wk, Wv, Wt, 768, 768, 768);
  transpose_cvt<<<dim3(8, 6, 3), 256, 0, stream>>>(LWq, LWk, LWv, LWt, 192, 192, 256);

  // q pre-scaled into exp2 domain: 1/(8 ln2), layout-q: 1/(4 ln2)
  proj_gemm<768, 768, 768, 64, 0><<<dim3(64, 6, 3), 256, 0, stream>>>(
      Xb, Wt, bq, bk, bv, qcb, kcb, vtb, 0.125f * INVLN2);
  proj_gemm<192, 192, 256, 16, 64><<<dim3(64, 2, 3), 256, 0, stream>>>(
      LXb, LWt, Lbq, Lbk, Lbv, qcb, kcb, vtb, 0.25f * INVLN2);

  attn_kernel<<<dim3(16, 48), 256, 0, stream>>>(qcb, kcb, vtb, mxb, out, out2);
}